// Round 1
// baseline (621.976 us; speedup 1.0000x reference)
//
#include <hip/hip_runtime.h>
#include <hip/hip_bf16.h>
#include <math.h>

typedef __attribute__((ext_vector_type(8))) short bf16x8;
typedef __attribute__((ext_vector_type(4))) float f32x4;

constexpr int cB = 2, cS = 2048, cH = 16, cD = 64, cIn = 1024, cM = 1024;

__device__ __forceinline__ short f2bf(float f) {
    union { float f; unsigned u; } v; v.f = f;
    unsigned r = v.u + 0x7fffu + ((v.u >> 16) & 1u);   // round-to-nearest-even
    return (short)(r >> 16);
}

// ---------------------------------------------------------------------------
// Kernel 1: relative-position bias table  bt[idx][h], idx = (key - query) + 2047
// ---------------------------------------------------------------------------
__global__ void bias_table_kernel(const float* __restrict__ rel_bias,
                                  float* __restrict__ bt) {
    int idx = blockIdx.x * blockDim.x + threadIdx.x;
    if (idx >= 4095) return;
    int delta = idx - 2047;                 // memory - context
    int rb = (delta > 0) ? 16 : 0;          // num_buckets//2 = 16
    int ar = delta < 0 ? -delta : delta;
    int bucket;
    if (ar < 8) {
        bucket = rb + ar;
    } else {
        // 8 + log(ar/8)/log(16) * 8, clamped at 15, truncated like astype(int32)
        float rl = 8.0f + logf((float)ar * 0.125f) * 2.8853900817779268f;
        rl = fminf(rl, 15.0f);
        bucket = rb + (int)rl;
    }
    #pragma unroll
    for (int h = 0; h < cH; h++) bt[idx * cH + h] = rel_bias[bucket * cH + h];
}

// ---------------------------------------------------------------------------
// Kernel 2: QKV projection.  C[4096x1024] = hidden @ W{q,k,v}, bf16 out in
// [B][H][S][D] layout; Q scaled by 1/8. 64x64 tile per 256-thread block.
// ---------------------------------------------------------------------------
__global__ __launch_bounds__(256) void qkv_kernel(
    const float* __restrict__ hidden, const float* __restrict__ Wq,
    const float* __restrict__ Wk, const float* __restrict__ Wv,
    short* __restrict__ qkv) {
    const int z = blockIdx.z;
    const float* W = (z == 0) ? Wq : (z == 1) ? Wk : Wv;
    short* out = qkv + (size_t)z * ((size_t)cB * cH * cS * cD);
    const float scale = (z == 0) ? 0.125f : 1.0f;
    const int r0 = blockIdx.y * 64;
    const int c0 = blockIdx.x * 64;

    __shared__ short sA[64][40];   // [row][k], +8 pad keeps 16B align, breaks conflicts
    __shared__ short sBt[64][40];  // [col][k] (B transposed so frag reads are contiguous)

    const int tid = threadIdx.x;
    const int wave = tid >> 6, lane = tid & 63;
    const int m16 = lane & 15, g = lane >> 4;
    const int arow = tid >> 2, acg = (tid & 3) << 3;  // A: 64 rows x 32 k
    const int bkr = tid >> 3, bcg = (tid & 7) << 3;   // B: 32 k x 64 cols

    f32x4 acc[4] = {};

    for (int k0 = 0; k0 < cIn; k0 += 32) {
        __syncthreads();
        {   // stage A (fp32 -> bf16)
            const float* src = hidden + (size_t)(r0 + arow) * cIn + k0 + acg;
            float4 x = ((const float4*)src)[0];
            float4 y = ((const float4*)src)[1];
            union { bf16x8 v; short s[8]; } p;
            p.s[0] = f2bf(x.x); p.s[1] = f2bf(x.y); p.s[2] = f2bf(x.z); p.s[3] = f2bf(x.w);
            p.s[4] = f2bf(y.x); p.s[5] = f2bf(y.y); p.s[6] = f2bf(y.z); p.s[7] = f2bf(y.w);
            *(bf16x8*)&sA[arow][acg] = p.v;
        }
        {   // stage B transposed (fp32 -> bf16)
            const float* src = W + (size_t)(k0 + bkr) * cM + c0 + bcg;
            float4 x = ((const float4*)src)[0];
            float4 y = ((const float4*)src)[1];
            sBt[bcg + 0][bkr] = f2bf(x.x); sBt[bcg + 1][bkr] = f2bf(x.y);
            sBt[bcg + 2][bkr] = f2bf(x.z); sBt[bcg + 3][bkr] = f2bf(x.w);
            sBt[bcg + 4][bkr] = f2bf(y.x); sBt[bcg + 5][bkr] = f2bf(y.y);
            sBt[bcg + 6][bkr] = f2bf(y.z); sBt[bcg + 7][bkr] = f2bf(y.w);
        }
        __syncthreads();
        bf16x8 af = *(const bf16x8*)&sA[wave * 16 + m16][g * 8];
        #pragma unroll
        for (int nt = 0; nt < 4; nt++) {
            bf16x8 bfr = *(const bf16x8*)&sBt[nt * 16 + m16][g * 8];
            acc[nt] = __builtin_amdgcn_mfma_f32_16x16x32_bf16(af, bfr, acc[nt], 0, 0, 0);
        }
    }
    #pragma unroll
    for (int nt = 0; nt < 4; nt++) {
        #pragma unroll
        for (int r = 0; r < 4; r++) {
            int row = r0 + wave * 16 + g * 4 + r;     // b*S + s
            int col = c0 + nt * 16 + m16;             // h*64 + d
            int bb = row >> 11, s = row & 2047;
            int hh = col >> 6, d = col & 63;
            out[(((size_t)bb * cH + hh) * cS + s) * cD + d] = f2bf(acc[nt][r] * scale);
        }
    }
}

// ---------------------------------------------------------------------------
// Kernel 3: flash attention. Block = (b, h, 64 q rows), 4 waves x 16 rows.
// ---------------------------------------------------------------------------
__global__ __launch_bounds__(256) void attn_kernel(
    const short* __restrict__ qkv, const int* __restrict__ mask,
    const float* __restrict__ bias_t, short* __restrict__ ctx) {
    const int b = blockIdx.z, h = blockIdx.y;
    const int q0 = blockIdx.x * 64;
    const size_t plane = (size_t)cB * cH * cS * cD;
    const size_t hoff = ((size_t)b * cH + h) * cS * cD;
    const short* Qp = qkv + hoff;
    const short* Kp = qkv + plane + hoff;
    const short* Vp = qkv + 2 * plane + hoff;
    const int* mp = mask + b * cS;

    const int tid = threadIdx.x;
    const int wave = tid >> 6, lane = tid & 63;
    const int m16 = lane & 15, g = lane >> 4;

    __shared__ short Vt[64][40];        // [d][key] transposed V tile (32 keys)
    __shared__ short pAs[4][16][40];    // per-wave P in A-operand layout [q][key]

    const int qrow16 = q0 + wave * 16 + m16;
    bf16x8 qf0 = *(const bf16x8*)(Qp + (size_t)qrow16 * cD + g * 8);
    bf16x8 qf1 = *(const bf16x8*)(Qp + (size_t)qrow16 * cD + 32 + g * 8);

    f32x4 o0 = {}, o1 = {}, o2 = {}, o3 = {};
    float mrow[4] = {-3.0e38f, -3.0e38f, -3.0e38f, -3.0e38f};
    float lrow[4] = {0.f, 0.f, 0.f, 0.f};

    const int vkr = tid >> 3, vdg = (tid & 7) << 3;

    for (int kt = 0; kt < cS; kt += 32) {
        __syncthreads();
        {   // stage V[kt..kt+32][0..64] transposed
            bf16x8 vv = *(const bf16x8*)(Vp + (size_t)(kt + vkr) * cD + vdg);
            #pragma unroll
            for (int j = 0; j < 8; j++) Vt[vdg + j][vkr] = vv[j];
        }
        __syncthreads();

        // scores for 16 q x 32 keys
        f32x4 s0 = {}, s1 = {};
        const short* kb0 = Kp + (size_t)(kt + m16) * cD + g * 8;
        const short* kb1 = Kp + (size_t)(kt + 16 + m16) * cD + g * 8;
        bf16x8 kf00 = *(const bf16x8*)kb0;
        bf16x8 kf01 = *(const bf16x8*)(kb0 + 32);
        bf16x8 kf10 = *(const bf16x8*)kb1;
        bf16x8 kf11 = *(const bf16x8*)(kb1 + 32);
        s0 = __builtin_amdgcn_mfma_f32_16x16x32_bf16(qf0, kf00, s0, 0, 0, 0);
        s0 = __builtin_amdgcn_mfma_f32_16x16x32_bf16(qf1, kf01, s0, 0, 0, 0);
        s1 = __builtin_amdgcn_mfma_f32_16x16x32_bf16(qf0, kf10, s1, 0, 0, 0);
        s1 = __builtin_amdgcn_mfma_f32_16x16x32_bf16(qf1, kf11, s1, 0, 0, 0);

        const int key0 = kt + m16, key1 = kt + 16 + m16;
        const float madd0 = (1.0f - (float)mp[key0]) * -3.0e38f;
        const float madd1 = (1.0f - (float)mp[key1]) * -3.0e38f;

        float x0[4], x1[4], mx[4];
        #pragma unroll
        for (int r = 0; r < 4; r++) {
            int qrow = q0 + wave * 16 + g * 4 + r;   // C-layout row
            x0[r] = s0[r] + bias_t[(key0 - qrow + 2047) * cH + h] + madd0;
            x1[r] = s1[r] + bias_t[(key1 - qrow + 2047) * cH + h] + madd1;
            mx[r] = fmaxf(x0[r], x1[r]);
        }
        #pragma unroll
        for (int off = 1; off < 16; off <<= 1) {
            #pragma unroll
            for (int r = 0; r < 4; r++) mx[r] = fmaxf(mx[r], __shfl_xor(mx[r], off, 64));
        }
        float alpha[4], rs[4];
        #pragma unroll
        for (int r = 0; r < 4; r++) {
            float nm = fmaxf(mrow[r], mx[r]);
            alpha[r] = __expf(mrow[r] - nm);
            mrow[r] = nm;
            x0[r] = __expf(x0[r] - nm);
            x1[r] = __expf(x1[r] - nm);
            rs[r] = x0[r] + x1[r];
        }
        #pragma unroll
        for (int off = 1; off < 16; off <<= 1) {
            #pragma unroll
            for (int r = 0; r < 4; r++) rs[r] += __shfl_xor(rs[r], off, 64);
        }
        #pragma unroll
        for (int r = 0; r < 4; r++) {
            lrow[r] = lrow[r] * alpha[r] + rs[r];
            o0[r] *= alpha[r]; o1[r] *= alpha[r]; o2[r] *= alpha[r]; o3[r] *= alpha[r];
            pAs[wave][g * 4 + r][m16]      = f2bf(x0[r]);   // C-layout -> [q][key]
            pAs[wave][g * 4 + r][16 + m16] = f2bf(x1[r]);
        }
        __syncthreads();
        bf16x8 pf  = *(const bf16x8*)&pAs[wave][m16][g * 8];   // A-layout read
        bf16x8 vf0 = *(const bf16x8*)&Vt[ 0 + m16][g * 8];
        bf16x8 vf1 = *(const bf16x8*)&Vt[16 + m16][g * 8];
        bf16x8 vf2 = *(const bf16x8*)&Vt[32 + m16][g * 8];
        bf16x8 vf3 = *(const bf16x8*)&Vt[48 + m16][g * 8];
        o0 = __builtin_amdgcn_mfma_f32_16x16x32_bf16(pf, vf0, o0, 0, 0, 0);
        o1 = __builtin_amdgcn_mfma_f32_16x16x32_bf16(pf, vf1, o1, 0, 0, 0);
        o2 = __builtin_amdgcn_mfma_f32_16x16x32_bf16(pf, vf2, o2, 0, 0, 0);
        o3 = __builtin_amdgcn_mfma_f32_16x16x32_bf16(pf, vf3, o3, 0, 0, 0);
    }

    #pragma unroll
    for (int r = 0; r < 4; r++) {
        float inv = 1.0f / lrow[r];
        int s = q0 + wave * 16 + g * 4 + r;
        size_t base = ((size_t)b * cS + s) * cM + h * cD;
        ctx[base +  0 + m16] = f2bf(o0[r] * inv);
        ctx[base + 16 + m16] = f2bf(o1[r] * inv);
        ctx[base + 32 + m16] = f2bf(o2[r] * inv);
        ctx[base + 48 + m16] = f2bf(o3[r] * inv);
    }
}

// ---------------------------------------------------------------------------
// Kernel 4: out = ctx(bf16) @ Wo(fp32->bf16), fp32 row-major out
// ---------------------------------------------------------------------------
__global__ __launch_bounds__(256) void oproj_kernel(
    const short* __restrict__ ctx, const float* __restrict__ Wo,
    float* __restrict__ out) {
    const int r0 = blockIdx.y * 64, c0 = blockIdx.x * 64;
    __shared__ short sA[64][40];
    __shared__ short sBt[64][40];
    const int tid = threadIdx.x, wave = tid >> 6, lane = tid & 63;
    const int m16 = lane & 15, g = lane >> 4;
    const int arow = tid >> 2, acg = (tid & 3) << 3;
    const int bkr = tid >> 3, bcg = (tid & 7) << 3;
    f32x4 acc[4] = {};

    for (int k0 = 0; k0 < cIn; k0 += 32) {
        __syncthreads();
        *(bf16x8*)&sA[arow][acg] =
            *(const bf16x8*)(ctx + (size_t)(r0 + arow) * cIn + k0 + acg);
        {
            const float* src = Wo + (size_t)(k0 + bkr) * cM + c0 + bcg;
            float4 x = ((const float4*)src)[0];
            float4 y = ((const float4*)src)[1];
            sBt[bcg + 0][bkr] = f2bf(x.x); sBt[bcg + 1][bkr] = f2bf(x.y);
            sBt[bcg + 2][bkr] = f2bf(x.z); sBt[bcg + 3][bkr] = f2bf(x.w);
            sBt[bcg + 4][bkr] = f2bf(y.x); sBt[bcg + 5][bkr] = f2bf(y.y);
            sBt[bcg + 6][bkr] = f2bf(y.z); sBt[bcg + 7][bkr] = f2bf(y.w);
        }
        __syncthreads();
        bf16x8 af = *(const bf16x8*)&sA[wave * 16 + m16][g * 8];
        #pragma unroll
        for (int nt = 0; nt < 4; nt++) {
            bf16x8 bfr = *(const bf16x8*)&sBt[nt * 16 + m16][g * 8];
            acc[nt] = __builtin_amdgcn_mfma_f32_16x16x32_bf16(af, bfr, acc[nt], 0, 0, 0);
        }
    }
    #pragma unroll
    for (int nt = 0; nt < 4; nt++) {
        #pragma unroll
        for (int r = 0; r < 4; r++) {
            out[(size_t)(r0 + wave * 16 + g * 4 + r) * cM + c0 + nt * 16 + m16] =
                acc[nt][r];
        }
    }
}

extern "C" void kernel_launch(void* const* d_in, const int* in_sizes, int n_in,
                              void* d_out, int out_size, void* d_ws, size_t ws_size,
                              hipStream_t stream) {
    const float* hidden   = (const float*)d_in[0];
    const int*   mask     = (const int*)d_in[1];
    const float* Wq       = (const float*)d_in[2];
    const float* Wk       = (const float*)d_in[3];
    const float* Wv       = (const float*)d_in[4];
    const float* Wo       = (const float*)d_in[5];
    const float* rel_bias = (const float*)d_in[6];
    float* out = (float*)d_out;

    // workspace layout (bf16 stored as short):
    // qkv: 3 * B*H*S*D = 3*4M shorts (24 MB), ctx: 4M shorts (8 MB), bias: 262 KB
    short* qkv = (short*)d_ws;
    short* ctx = qkv + (size_t)3 * cB * cH * cS * cD;
    float* bias_t = (float*)(ctx + (size_t)cB * cS * cM);

    bias_table_kernel<<<16, 256, 0, stream>>>(rel_bias, bias_t);
    qkv_kernel<<<dim3(16, 64, 3), 256, 0, stream>>>(hidden, Wq, Wk, Wv, qkv);
    attn_kernel<<<dim3(32, cH, cB), 256, 0, stream>>>(qkv, mask, bias_t, ctx);
    oproj_kernel<<<dim3(16, 64), 256, 0, stream>>>(ctx, Wo, out);
}

// Round 2
// 506.750 us; speedup vs baseline: 1.2274x; 1.2274x over previous
//
#include <hip/hip_runtime.h>
#include <hip/hip_bf16.h>
#include <math.h>

typedef __attribute__((ext_vector_type(8))) short bf16x8;
typedef __attribute__((ext_vector_type(4))) float f32x4;

constexpr int cB = 2, cS = 2048, cH = 16, cD = 64, cIn = 1024, cM = 1024;

__device__ __forceinline__ short f2bf(float f) {
    union { float f; unsigned u; } v; v.f = f;
    unsigned r = v.u + 0x7fffu + ((v.u >> 16) & 1u);   // round-to-nearest-even
    return (short)(r >> 16);
}

__device__ __forceinline__ f32x4 mfma16(bf16x8 a, bf16x8 b, f32x4 c) {
    return __builtin_amdgcn_mfma_f32_16x16x32_bf16(a, b, c, 0, 0, 0);
}

// ---------------------------------------------------------------------------
// Kernel 1: relative-position bias table, TRANSPOSED: bt[h][2048 + delta],
// delta = key - query in [-2047, 2047]; stride 4096 per head.
// ---------------------------------------------------------------------------
__global__ void bias_table_kernel(const float* __restrict__ rel_bias,
                                  float* __restrict__ bt) {
    int idx = blockIdx.x * blockDim.x + threadIdx.x;
    if (idx >= 4095) return;
    int delta = idx - 2047;                 // memory - context
    int rb = (delta > 0) ? 16 : 0;          // num_buckets//2 = 16
    int ar = delta < 0 ? -delta : delta;
    int bucket;
    if (ar < 8) {
        bucket = rb + ar;
    } else {
        // 8 + log(ar/8)/log(16) * 8, clamped at 15, truncated like astype(int32)
        float rl = 8.0f + logf((float)ar * 0.125f) * 2.8853900817779268f;
        rl = fminf(rl, 15.0f);
        bucket = rb + (int)rl;
    }
    #pragma unroll
    for (int h = 0; h < cH; h++)
        bt[h * 4096 + 2048 + delta] = rel_bias[bucket * cH + h];
}

// ---------------------------------------------------------------------------
// Kernel 2: QKV projection. C[4096x1024] = hidden @ W{q,k,v}, bf16 out.
// z==0 (Q, scaled 1/8) and z==1 (K): [b][h][s][d] layout.
// z==2 (V): TRANSPOSED [b][h][d][s] layout via LDS-transpose epilogue, so the
//           attention kernel can vector-load V^T B-fragments from global.
// ---------------------------------------------------------------------------
__global__ __launch_bounds__(256) void qkv_kernel(
    const float* __restrict__ hidden, const float* __restrict__ Wq,
    const float* __restrict__ Wk, const float* __restrict__ Wv,
    short* __restrict__ qkv) {
    const int z = blockIdx.z;
    const float* W = (z == 0) ? Wq : (z == 1) ? Wk : Wv;
    short* out = qkv + (size_t)z * ((size_t)cB * cH * cS * cD);
    const float scale = (z == 0) ? 0.125f : 1.0f;
    const int r0 = blockIdx.y * 64;
    const int c0 = blockIdx.x * 64;

    __shared__ short smem[2 * 64 * 40];
    short (*sA)[40]  = (short(*)[40])smem;            // [row][k]
    short (*sBt)[40] = (short(*)[40])(smem + 64 * 40); // [col][k]

    const int tid = threadIdx.x;
    const int wave = tid >> 6, lane = tid & 63;
    const int m16 = lane & 15, g = lane >> 4;
    const int arow = tid >> 2, acg = (tid & 3) << 3;  // A: 64 rows x 32 k
    const int bkr = tid >> 3, bcg = (tid & 7) << 3;   // B: 32 k x 64 cols

    f32x4 acc[4] = {};

    for (int k0 = 0; k0 < cIn; k0 += 32) {
        __syncthreads();
        {   // stage A (fp32 -> bf16)
            const float* src = hidden + (size_t)(r0 + arow) * cIn + k0 + acg;
            float4 x = ((const float4*)src)[0];
            float4 y = ((const float4*)src)[1];
            union { bf16x8 v; short s[8]; } p;
            p.s[0] = f2bf(x.x); p.s[1] = f2bf(x.y); p.s[2] = f2bf(x.z); p.s[3] = f2bf(x.w);
            p.s[4] = f2bf(y.x); p.s[5] = f2bf(y.y); p.s[6] = f2bf(y.z); p.s[7] = f2bf(y.w);
            *(bf16x8*)&sA[arow][acg] = p.v;
        }
        {   // stage B transposed (fp32 -> bf16)
            const float* src = W + (size_t)(k0 + bkr) * cM + c0 + bcg;
            float4 x = ((const float4*)src)[0];
            float4 y = ((const float4*)src)[1];
            sBt[bcg + 0][bkr] = f2bf(x.x); sBt[bcg + 1][bkr] = f2bf(x.y);
            sBt[bcg + 2][bkr] = f2bf(x.z); sBt[bcg + 3][bkr] = f2bf(x.w);
            sBt[bcg + 4][bkr] = f2bf(y.x); sBt[bcg + 5][bkr] = f2bf(y.y);
            sBt[bcg + 6][bkr] = f2bf(y.z); sBt[bcg + 7][bkr] = f2bf(y.w);
        }
        __syncthreads();
        bf16x8 af = *(const bf16x8*)&sA[wave * 16 + m16][g * 8];
        #pragma unroll
        for (int nt = 0; nt < 4; nt++) {
            bf16x8 bfr = *(const bf16x8*)&sBt[nt * 16 + m16][g * 8];
            acc[nt] = mfma16(af, bfr, acc[nt]);
        }
    }

    if (z != 2) {
        #pragma unroll
        for (int nt = 0; nt < 4; nt++) {
            #pragma unroll
            for (int r = 0; r < 4; r++) {
                int row = r0 + wave * 16 + g * 4 + r;     // b*S + s
                int col = c0 + nt * 16 + m16;             // h*64 + d
                int bb = row >> 11, s = row & 2047;
                int hh = col >> 6, d = col & 63;
                out[(((size_t)bb * cH + hh) * cS + s) * cD + d] = f2bf(acc[nt][r] * scale);
            }
        }
    } else {
        // V^T epilogue: transpose 64x64 tile through LDS, store [b][h][d][s]
        __syncthreads();
        short (*sT)[72] = (short(*)[72])smem;    // 64 x 72 shorts = 9216 B <= 10240
        #pragma unroll
        for (int nt = 0; nt < 4; nt++) {
            #pragma unroll
            for (int r = 0; r < 4; r++)
                sT[nt * 16 + m16][wave * 16 + g * 4 + r] = f2bf(acc[nt][r]);
        }
        __syncthreads();
        const int dcol = tid >> 2;              // 0..63 within tile cols
        const int sg = (tid & 3) << 4;          // 0,16,32,48 within tile rows
        const int bb = r0 >> 11, s0r = (r0 & 2047) + sg;
        const int hh = c0 >> 6;
        short* dst = out + ((size_t)(bb * cH + hh) * cD + dcol) * cS + s0r;
        *(bf16x8*)(dst)     = *(const bf16x8*)&sT[dcol][sg];
        *(bf16x8*)(dst + 8) = *(const bf16x8*)&sT[dcol][sg + 8];
    }
}

// ---------------------------------------------------------------------------
// Kernel 3: flash attention, barrier-free inner loop.
// Block = (b, h, 64 q rows), 4 independent waves x 16 q rows.
// No max-subtraction softmax (|scores| <= ~10 -> exp cannot overflow; masked
// keys give exp(-3e38)=0 naturally). Denominator reduced once after the loop.
// ---------------------------------------------------------------------------
__global__ __launch_bounds__(256) void attn_kernel(
    const short* __restrict__ qkv, const int* __restrict__ mask,
    const float* __restrict__ bias_t, short* __restrict__ ctx) {
    const int b = blockIdx.z, h = blockIdx.y;
    const int q0 = blockIdx.x * 64;
    const size_t plane = (size_t)cB * cH * cS * cD;
    const size_t hoff = ((size_t)b * cH + h) * cS * cD;
    const short* Qp  = qkv + hoff;
    const short* Kp  = qkv + plane + hoff;
    const short* VTp = qkv + 2 * plane + hoff;   // [d][s]
    const int* mp = mask + b * cS;
    const float* bh = bias_t + h * 4096 + 2048;  // bh[key - qrow]

    const int tid = threadIdx.x;
    const int wave = tid >> 6, lane = tid & 63;
    const int m16 = lane & 15, g = lane >> 4;

    __shared__ short pAs[4][16][40];             // per-wave P: C-layout -> A-layout

    const int qrow16 = q0 + wave * 16 + m16;
    bf16x8 qf0 = *(const bf16x8*)(Qp + (size_t)qrow16 * cD + g * 8);
    bf16x8 qf1 = *(const bf16x8*)(Qp + (size_t)qrow16 * cD + 32 + g * 8);

    f32x4 o0 = {}, o1 = {}, o2 = {}, o3 = {};
    float lsum[4] = {0.f, 0.f, 0.f, 0.f};
    int qr[4];
    #pragma unroll
    for (int r = 0; r < 4; r++) qr[r] = q0 + wave * 16 + g * 4 + r;

    for (int kt = 0; kt < cS; kt += 32) {
        // ---- QK^T: 16 q x 32 keys
        f32x4 s0 = {}, s1 = {};
        const short* kb0 = Kp + (size_t)(kt + m16) * cD + g * 8;
        bf16x8 kf00 = *(const bf16x8*)(kb0);
        bf16x8 kf01 = *(const bf16x8*)(kb0 + 32);
        bf16x8 kf10 = *(const bf16x8*)(kb0 + 16 * cD);
        bf16x8 kf11 = *(const bf16x8*)(kb0 + 16 * cD + 32);
        s0 = mfma16(qf0, kf00, s0); s0 = mfma16(qf1, kf01, s0);
        s1 = mfma16(qf0, kf10, s1); s1 = mfma16(qf1, kf11, s1);

        const int key0 = kt + m16;
        const float madd0 = (1.0f - (float)mp[key0]) * -3.0e38f;
        const float madd1 = (1.0f - (float)mp[key0 + 16]) * -3.0e38f;

        // ---- softmax numerator (no max subtraction), stage P to A-layout
        #pragma unroll
        for (int r = 0; r < 4; r++) {
            float p0 = __expf(s0[r] + bh[key0 - qr[r]] + madd0);
            float p1 = __expf(s1[r] + bh[key0 + 16 - qr[r]] + madd1);
            lsum[r] += p0 + p1;
            pAs[wave][g * 4 + r][m16]      = f2bf(p0);
            pAs[wave][g * 4 + r][16 + m16] = f2bf(p1);
        }
        __builtin_amdgcn_wave_barrier();   // pin LDS write->read order (in-order DS pipe)
        bf16x8 pf = *(const bf16x8*)&pAs[wave][m16][g * 8];
        __builtin_amdgcn_wave_barrier();

        // ---- PV: V^T fragments straight from global (precomputed transpose)
        const short* vb = VTp + (size_t)m16 * cS + kt + g * 8;
        bf16x8 vf0 = *(const bf16x8*)(vb);
        bf16x8 vf1 = *(const bf16x8*)(vb + (size_t)16 * cS);
        bf16x8 vf2 = *(const bf16x8*)(vb + (size_t)32 * cS);
        bf16x8 vf3 = *(const bf16x8*)(vb + (size_t)48 * cS);
        o0 = mfma16(pf, vf0, o0); o1 = mfma16(pf, vf1, o1);
        o2 = mfma16(pf, vf2, o2); o3 = mfma16(pf, vf3, o3);
    }

    // ---- one denominator reduction for the whole row (16-lane groups)
    #pragma unroll
    for (int off = 1; off < 16; off <<= 1) {
        #pragma unroll
        for (int r = 0; r < 4; r++) lsum[r] += __shfl_xor(lsum[r], off, 64);
    }
    #pragma unroll
    for (int r = 0; r < 4; r++) {
        float inv = 1.0f / lsum[r];
        int s = qr[r];
        size_t base = ((size_t)b * cS + s) * cM + h * cD;
        ctx[base +  0 + m16] = f2bf(o0[r] * inv);
        ctx[base + 16 + m16] = f2bf(o1[r] * inv);
        ctx[base + 32 + m16] = f2bf(o2[r] * inv);
        ctx[base + 48 + m16] = f2bf(o3[r] * inv);
    }
}

// ---------------------------------------------------------------------------
// Kernel 4: out = ctx(bf16) @ Wo(fp32->bf16), fp32 row-major out
// ---------------------------------------------------------------------------
__global__ __launch_bounds__(256) void oproj_kernel(
    const short* __restrict__ ctx, const float* __restrict__ Wo,
    float* __restrict__ out) {
    const int r0 = blockIdx.y * 64, c0 = blockIdx.x * 64;
    __shared__ short sA[64][40];
    __shared__ short sBt[64][40];
    const int tid = threadIdx.x, wave = tid >> 6, lane = tid & 63;
    const int m16 = lane & 15, g = lane >> 4;
    const int arow = tid >> 2, acg = (tid & 3) << 3;
    const int bkr = tid >> 3, bcg = (tid & 7) << 3;
    f32x4 acc[4] = {};

    for (int k0 = 0; k0 < cIn; k0 += 32) {
        __syncthreads();
        *(bf16x8*)&sA[arow][acg] =
            *(const bf16x8*)(ctx + (size_t)(r0 + arow) * cIn + k0 + acg);
        {
            const float* src = Wo + (size_t)(k0 + bkr) * cM + c0 + bcg;
            float4 x = ((const float4*)src)[0];
            float4 y = ((const float4*)src)[1];
            sBt[bcg + 0][bkr] = f2bf(x.x); sBt[bcg + 1][bkr] = f2bf(x.y);
            sBt[bcg + 2][bkr] = f2bf(x.z); sBt[bcg + 3][bkr] = f2bf(x.w);
            sBt[bcg + 4][bkr] = f2bf(y.x); sBt[bcg + 5][bkr] = f2bf(y.y);
            sBt[bcg + 6][bkr] = f2bf(y.z); sBt[bcg + 7][bkr] = f2bf(y.w);
        }
        __syncthreads();
        bf16x8 af = *(const bf16x8*)&sA[wave * 16 + m16][g * 8];
        #pragma unroll
        for (int nt = 0; nt < 4; nt++) {
            bf16x8 bfr = *(const bf16x8*)&sBt[nt * 16 + m16][g * 8];
            acc[nt] = mfma16(af, bfr, acc[nt]);
        }
    }
    #pragma unroll
    for (int nt = 0; nt < 4; nt++) {
        #pragma unroll
        for (int r = 0; r < 4; r++) {
            out[(size_t)(r0 + wave * 16 + g * 4 + r) * cM + c0 + nt * 16 + m16] =
                acc[nt][r];
        }
    }
}

extern "C" void kernel_launch(void* const* d_in, const int* in_sizes, int n_in,
                              void* d_out, int out_size, void* d_ws, size_t ws_size,
                              hipStream_t stream) {
    const float* hidden   = (const float*)d_in[0];
    const int*   mask     = (const int*)d_in[1];
    const float* Wq       = (const float*)d_in[2];
    const float* Wk       = (const float*)d_in[3];
    const float* Wv       = (const float*)d_in[4];
    const float* Wo       = (const float*)d_in[5];
    const float* rel_bias = (const float*)d_in[6];
    float* out = (float*)d_out;

    // workspace layout (bf16 stored as short):
    // qkv: 3 * B*H*S*D shorts (24 MB; V plane transposed), ctx: 8 MB, bias: 256 KB
    short* qkv = (short*)d_ws;
    short* ctx = qkv + (size_t)3 * cB * cH * cS * cD;
    float* bias_t = (float*)(ctx + (size_t)cB * cS * cM);

    bias_table_kernel<<<16, 256, 0, stream>>>(rel_bias, bias_t);
    qkv_kernel<<<dim3(16, 64, 3), 256, 0, stream>>>(hidden, Wq, Wk, Wv, qkv);
    attn_kernel<<<dim3(32, cH, cB), 256, 0, stream>>>(qkv, mask, bias_t, ctx);
    oproj_kernel<<<dim3(16, 64), 256, 0, stream>>>(ctx, Wo, out);
}

// Round 3
// 342.395 us; speedup vs baseline: 1.8165x; 1.4800x over previous
//
#include <hip/hip_runtime.h>
#include <hip/hip_bf16.h>
#include <math.h>

typedef __attribute__((ext_vector_type(8))) short bf16x8;
typedef __attribute__((ext_vector_type(4))) float f32x4;

constexpr int cB = 2, cS = 2048, cH = 16, cD = 64, cIn = 1024, cM = 1024;

__device__ __forceinline__ short f2bf(float f) {
    union { float f; unsigned u; } v; v.f = f;
    unsigned r = v.u + 0x7fffu + ((v.u >> 16) & 1u);   // round-to-nearest-even
    return (short)(r >> 16);
}

__device__ __forceinline__ f32x4 mfma16(bf16x8 a, bf16x8 b, f32x4 c) {
    return __builtin_amdgcn_mfma_f32_16x16x32_bf16(a, b, c, 0, 0, 0);
}

// ---------------------------------------------------------------------------
// Kernel 1: relative-position bias table, TRANSPOSED: bt[h][2048 + delta],
// delta = key - query in [-2047, 2047]; stride 4096 per head.
// ---------------------------------------------------------------------------
__global__ void bias_table_kernel(const float* __restrict__ rel_bias,
                                  float* __restrict__ bt) {
    int idx = blockIdx.x * blockDim.x + threadIdx.x;
    if (idx >= 4095) return;
    int delta = idx - 2047;                 // memory - context
    int rb = (delta > 0) ? 16 : 0;          // num_buckets//2 = 16
    int ar = delta < 0 ? -delta : delta;
    int bucket;
    if (ar < 8) {
        bucket = rb + ar;
    } else {
        float rl = 8.0f + logf((float)ar * 0.125f) * 2.8853900817779268f;
        rl = fminf(rl, 15.0f);
        bucket = rb + (int)rl;
    }
    #pragma unroll
    for (int h = 0; h < cH; h++)
        bt[h * 4096 + 2048 + delta] = rel_bias[bucket * cH + h];
}

// ---------------------------------------------------------------------------
// Kernel 2: QKV projection. C[4096x1024] = hidden @ W{q,k,v}, bf16 out.
// z==0 (Q, scaled 1/8) and z==1 (K): [b][h][s][d] layout.
// z==2 (V): TRANSPOSED [b][h][d][s] layout via LDS-transpose epilogue.
// ---------------------------------------------------------------------------
__global__ __launch_bounds__(256) void qkv_kernel(
    const float* __restrict__ hidden, const float* __restrict__ Wq,
    const float* __restrict__ Wk, const float* __restrict__ Wv,
    short* __restrict__ qkv) {
    const int z = blockIdx.z;
    const float* W = (z == 0) ? Wq : (z == 1) ? Wk : Wv;
    short* out = qkv + (size_t)z * ((size_t)cB * cH * cS * cD);
    const float scale = (z == 0) ? 0.125f : 1.0f;
    const int r0 = blockIdx.y * 64;
    const int c0 = blockIdx.x * 64;

    __shared__ short smem[2 * 64 * 40];
    short (*sA)[40]  = (short(*)[40])smem;             // [row][k]
    short (*sBt)[40] = (short(*)[40])(smem + 64 * 40); // [col][k]

    const int tid = threadIdx.x;
    const int wave = tid >> 6, lane = tid & 63;
    const int m16 = lane & 15, g = lane >> 4;
    const int arow = tid >> 2, acg = (tid & 3) << 3;  // A: 64 rows x 32 k
    const int bkr = tid >> 3, bcg = (tid & 7) << 3;   // B: 32 k x 64 cols

    f32x4 acc[4] = {};

    for (int k0 = 0; k0 < cIn; k0 += 32) {
        __syncthreads();
        {   // stage A (fp32 -> bf16)
            const float* src = hidden + (size_t)(r0 + arow) * cIn + k0 + acg;
            float4 x = ((const float4*)src)[0];
            float4 y = ((const float4*)src)[1];
            union { bf16x8 v; short s[8]; } p;
            p.s[0] = f2bf(x.x); p.s[1] = f2bf(x.y); p.s[2] = f2bf(x.z); p.s[3] = f2bf(x.w);
            p.s[4] = f2bf(y.x); p.s[5] = f2bf(y.y); p.s[6] = f2bf(y.z); p.s[7] = f2bf(y.w);
            *(bf16x8*)&sA[arow][acg] = p.v;
        }
        {   // stage B transposed (fp32 -> bf16)
            const float* src = W + (size_t)(k0 + bkr) * cM + c0 + bcg;
            float4 x = ((const float4*)src)[0];
            float4 y = ((const float4*)src)[1];
            sBt[bcg + 0][bkr] = f2bf(x.x); sBt[bcg + 1][bkr] = f2bf(x.y);
            sBt[bcg + 2][bkr] = f2bf(x.z); sBt[bcg + 3][bkr] = f2bf(x.w);
            sBt[bcg + 4][bkr] = f2bf(y.x); sBt[bcg + 5][bkr] = f2bf(y.y);
            sBt[bcg + 6][bkr] = f2bf(y.z); sBt[bcg + 7][bkr] = f2bf(y.w);
        }
        __syncthreads();
        bf16x8 af = *(const bf16x8*)&sA[wave * 16 + m16][g * 8];
        #pragma unroll
        for (int nt = 0; nt < 4; nt++) {
            bf16x8 bfr = *(const bf16x8*)&sBt[nt * 16 + m16][g * 8];
            acc[nt] = mfma16(af, bfr, acc[nt]);
        }
    }

    if (z != 2) {
        #pragma unroll
        for (int nt = 0; nt < 4; nt++) {
            #pragma unroll
            for (int r = 0; r < 4; r++) {
                int row = r0 + wave * 16 + g * 4 + r;     // b*S + s
                int col = c0 + nt * 16 + m16;             // h*64 + d
                int bb = row >> 11, s = row & 2047;
                int hh = col >> 6, d = col & 63;
                out[(((size_t)bb * cH + hh) * cS + s) * cD + d] = f2bf(acc[nt][r] * scale);
            }
        }
    } else {
        // V^T epilogue: transpose 64x64 tile through LDS, store [b][h][d][s]
        __syncthreads();
        short (*sT)[72] = (short(*)[72])smem;    // 64 x 72 shorts = 9216 B
        #pragma unroll
        for (int nt = 0; nt < 4; nt++) {
            #pragma unroll
            for (int r = 0; r < 4; r++)
                sT[nt * 16 + m16][wave * 16 + g * 4 + r] = f2bf(acc[nt][r]);
        }
        __syncthreads();
        const int dcol = tid >> 2;              // 0..63 within tile cols
        const int sg = (tid & 3) << 4;          // 0,16,32,48 within tile rows
        const int bb = r0 >> 11, s0r = (r0 & 2047) + sg;
        const int hh = c0 >> 6;
        short* dst = out + ((size_t)(bb * cH + hh) * cD + dcol) * cS + s0r;
        *(bf16x8*)(dst)     = *(const bf16x8*)&sT[dcol][sg];
        *(bf16x8*)(dst + 8) = *(const bf16x8*)&sT[dcol][sg + 8];
    }
}

// ---------------------------------------------------------------------------
// Kernel 3: flash attention with LDS-staged K/V tiles (64 keys/iter).
// Block = (b, h, 64 q rows), 4 waves x 16 q rows. K/V staged cooperatively
// (coalesced 16B/lane, deduped across the 4 waves); fragments from LDS.
// No max-subtraction softmax (|scores| <= ~10); one denom reduction at end.
// ---------------------------------------------------------------------------
__global__ __launch_bounds__(256) void attn_kernel(
    const short* __restrict__ qkv, const int* __restrict__ mask,
    const float* __restrict__ bias_t, short* __restrict__ ctx) {
    const int b = blockIdx.z, h = blockIdx.y;
    const int q0 = blockIdx.x * 64;
    const size_t plane = (size_t)cB * cH * cS * cD;
    const size_t hoff = ((size_t)b * cH + h) * cS * cD;
    const short* Qp  = qkv + hoff;
    const short* Kp  = qkv + plane + hoff;        // [s][d]
    const short* VTp = qkv + 2 * plane + hoff;    // [d][s]
    const int* mp = mask + b * cS;
    const float* bh = bias_t + h * 4096 + 2048;   // bh[key - qrow]

    const int tid = threadIdx.x;
    const int wave = tid >> 6, lane = tid & 63;
    const int m16 = lane & 15, g = lane >> 4;

    __shared__ short Kt[64][72];       // [key][d] pad8
    __shared__ short Vt[64][72];       // [d][key] pad8
    __shared__ short Ps[4][16][72];    // per-wave P in A-layout [q][key] pad8

    const int qrow16 = q0 + wave * 16 + m16;
    bf16x8 qf0 = *(const bf16x8*)(Qp + (size_t)qrow16 * cD + g * 8);
    bf16x8 qf1 = *(const bf16x8*)(Qp + (size_t)qrow16 * cD + 32 + g * 8);

    f32x4 o0 = {}, o1 = {}, o2 = {}, o3 = {};
    float lsum[4] = {0.f, 0.f, 0.f, 0.f};
    int qr[4];
    #pragma unroll
    for (int r = 0; r < 4; r++) qr[r] = q0 + wave * 16 + g * 4 + r;

    const int srow = tid >> 3;               // 0..31
    const int scol = (tid & 7) << 3;         // 0,8,..,56

    for (int kt = 0; kt < cS; kt += 64) {
        __syncthreads();
        // ---- stage K tile [64 keys][64 d] (coalesced 16B/lane, 2 rows blocks)
        *(bf16x8*)&Kt[srow][scol] =
            *(const bf16x8*)(Kp + (size_t)(kt + srow) * cD + scol);
        *(bf16x8*)&Kt[srow + 32][scol] =
            *(const bf16x8*)(Kp + (size_t)(kt + srow + 32) * cD + scol);
        // ---- stage V^T tile [64 d][64 keys]
        *(bf16x8*)&Vt[srow][scol] =
            *(const bf16x8*)(VTp + (size_t)srow * cS + kt + scol);
        *(bf16x8*)&Vt[srow + 32][scol] =
            *(const bf16x8*)(VTp + (size_t)(srow + 32) * cS + kt + scol);
        __syncthreads();

        // ---- QK^T: 16 q x 64 keys (8 MFMAs)
        f32x4 s[4];
        #pragma unroll
        for (int st = 0; st < 4; st++) {
            bf16x8 klo = *(const bf16x8*)&Kt[st * 16 + m16][g * 8];
            bf16x8 khi = *(const bf16x8*)&Kt[st * 16 + m16][32 + g * 8];
            f32x4 t = {};
            t = mfma16(qf0, klo, t);
            t = mfma16(qf1, khi, t);
            s[st] = t;
        }

        // ---- softmax numerator, stage P into A-layout
        #pragma unroll
        for (int st = 0; st < 4; st++) {
            const int key = kt + st * 16 + m16;
            const float madd = (1.0f - (float)mp[key]) * -3.0e38f;
            const float* bk = bh + key;
            #pragma unroll
            for (int r = 0; r < 4; r++) {
                float p = __expf(s[st][r] + bk[-qr[r]] + madd);
                lsum[r] += p;
                Ps[wave][g * 4 + r][st * 16 + m16] = f2bf(p);
            }
        }
        __builtin_amdgcn_wave_barrier();   // pin per-wave LDS write->read order
        bf16x8 pf0 = *(const bf16x8*)&Ps[wave][m16][g * 8];
        bf16x8 pf1 = *(const bf16x8*)&Ps[wave][m16][32 + g * 8];
        __builtin_amdgcn_wave_barrier();

        // ---- PV: 64 d outputs, contraction over 64 keys (8 MFMAs)
        #pragma unroll
        for (int nt = 0; nt < 4; nt++) {
            bf16x8 vlo = *(const bf16x8*)&Vt[nt * 16 + m16][g * 8];
            bf16x8 vhi = *(const bf16x8*)&Vt[nt * 16 + m16][32 + g * 8];
            f32x4* o = (nt == 0) ? &o0 : (nt == 1) ? &o1 : (nt == 2) ? &o2 : &o3;
            *o = mfma16(pf0, vlo, *o);
            *o = mfma16(pf1, vhi, *o);
        }
    }

    // ---- one denominator reduction for the whole row (16-lane groups)
    #pragma unroll
    for (int off = 1; off < 16; off <<= 1) {
        #pragma unroll
        for (int r = 0; r < 4; r++) lsum[r] += __shfl_xor(lsum[r], off, 64);
    }
    #pragma unroll
    for (int r = 0; r < 4; r++) {
        float inv = 1.0f / lsum[r];
        int s = qr[r];
        size_t base = ((size_t)b * cS + s) * cM + h * cD;
        ctx[base +  0 + m16] = f2bf(o0[r] * inv);
        ctx[base + 16 + m16] = f2bf(o1[r] * inv);
        ctx[base + 32 + m16] = f2bf(o2[r] * inv);
        ctx[base + 48 + m16] = f2bf(o3[r] * inv);
    }
}

// ---------------------------------------------------------------------------
// Kernel 4: out = ctx(bf16) @ Wo(fp32->bf16), fp32 row-major out
// ---------------------------------------------------------------------------
__global__ __launch_bounds__(256) void oproj_kernel(
    const short* __restrict__ ctx, const float* __restrict__ Wo,
    float* __restrict__ out) {
    const int r0 = blockIdx.y * 64, c0 = blockIdx.x * 64;
    __shared__ short sA[64][40];
    __shared__ short sBt[64][40];
    const int tid = threadIdx.x, wave = tid >> 6, lane = tid & 63;
    const int m16 = lane & 15, g = lane >> 4;
    const int arow = tid >> 2, acg = (tid & 3) << 3;
    const int bkr = tid >> 3, bcg = (tid & 7) << 3;
    f32x4 acc[4] = {};

    for (int k0 = 0; k0 < cIn; k0 += 32) {
        __syncthreads();
        *(bf16x8*)&sA[arow][acg] =
            *(const bf16x8*)(ctx + (size_t)(r0 + arow) * cIn + k0 + acg);
        {
            const float* src = Wo + (size_t)(k0 + bkr) * cM + c0 + bcg;
            float4 x = ((const float4*)src)[0];
            float4 y = ((const float4*)src)[1];
            sBt[bcg + 0][bkr] = f2bf(x.x); sBt[bcg + 1][bkr] = f2bf(x.y);
            sBt[bcg + 2][bkr] = f2bf(x.z); sBt[bcg + 3][bkr] = f2bf(x.w);
            sBt[bcg + 4][bkr] = f2bf(y.x); sBt[bcg + 5][bkr] = f2bf(y.y);
            sBt[bcg + 6][bkr] = f2bf(y.z); sBt[bcg + 7][bkr] = f2bf(y.w);
        }
        __syncthreads();
        bf16x8 af = *(const bf16x8*)&sA[wave * 16 + m16][g * 8];
        #pragma unroll
        for (int nt = 0; nt < 4; nt++) {
            bf16x8 bfr = *(const bf16x8*)&sBt[nt * 16 + m16][g * 8];
            acc[nt] = mfma16(af, bfr, acc[nt]);
        }
    }
    #pragma unroll
    for (int nt = 0; nt < 4; nt++) {
        #pragma unroll
        for (int r = 0; r < 4; r++) {
            out[(size_t)(r0 + wave * 16 + g * 4 + r) * cM + c0 + nt * 16 + m16] =
                acc[nt][r];
        }
    }
}

extern "C" void kernel_launch(void* const* d_in, const int* in_sizes, int n_in,
                              void* d_out, int out_size, void* d_ws, size_t ws_size,
                              hipStream_t stream) {
    const float* hidden   = (const float*)d_in[0];
    const int*   mask     = (const int*)d_in[1];
    const float* Wq       = (const float*)d_in[2];
    const float* Wk       = (const float*)d_in[3];
    const float* Wv       = (const float*)d_in[4];
    const float* Wo       = (const float*)d_in[5];
    const float* rel_bias = (const float*)d_in[6];
    float* out = (float*)d_out;

    short* qkv = (short*)d_ws;                                  // 24 MB bf16
    short* ctx = qkv + (size_t)3 * cB * cH * cS * cD;           // 8 MB bf16
    float* bias_t = (float*)(ctx + (size_t)cB * cS * cM);       // 256 KB

    bias_table_kernel<<<16, 256, 0, stream>>>(rel_bias, bias_t);
    qkv_kernel<<<dim3(16, 64, 3), 256, 0, stream>>>(hidden, Wq, Wk, Wv, qkv);
    attn_kernel<<<dim3(32, cH, cB), 256, 0, stream>>>(qkv, mask, bias_t, ctx);
    oproj_kernel<<<dim3(16, 64), 256, 0, stream>>>(ctx, Wo, out);
}

// Round 5
// 248.389 us; speedup vs baseline: 2.5040x; 1.3785x over previous
//
#include <hip/hip_runtime.h>
#include <hip/hip_bf16.h>
#include <math.h>

typedef __attribute__((ext_vector_type(8))) short bf16x8;
typedef __attribute__((ext_vector_type(4))) float f32x4;

constexpr int cB = 2, cS = 2048, cH = 16, cD = 64, cIn = 1024, cM = 1024;

union BfPack { bf16x8 v; short s[8]; };

__device__ __forceinline__ short f2bf(float f) {
    union { float f; unsigned u; } v; v.f = f;
    unsigned r = v.u + 0x7fffu + ((v.u >> 16) & 1u);   // round-to-nearest-even
    return (short)(r >> 16);
}

__device__ __forceinline__ f32x4 mfma16(bf16x8 a, bf16x8 b, f32x4 c) {
    return __builtin_amdgcn_mfma_f32_16x16x32_bf16(a, b, c, 0, 0, 0);
}

// async global->LDS, 16B/lane. LDS dest = wave-uniform base + lane*16 (HW rule);
// flat->AS3 truncation is the CK-verified route on gfx9-lineage.
__device__ __forceinline__ void async16(const short* g, short* l) {
    __builtin_amdgcn_global_load_lds(
        (const __attribute__((address_space(1))) unsigned*)(uintptr_t)g,
        (__attribute__((address_space(3))) unsigned*)(uintptr_t)l, 16, 0, 0);
}

// ---------------------------------------------------------------------------
// Kernel 1: relative-position bias table, TRANSPOSED: bt[h][2048 + delta]
// ---------------------------------------------------------------------------
__global__ void bias_table_kernel(const float* __restrict__ rel_bias,
                                  float* __restrict__ bt) {
    int idx = blockIdx.x * blockDim.x + threadIdx.x;
    if (idx >= 4095) return;
    int delta = idx - 2047;
    int rb = (delta > 0) ? 16 : 0;
    int ar = delta < 0 ? -delta : delta;
    int bucket;
    if (ar < 8) {
        bucket = rb + ar;
    } else {
        float rl = 8.0f + logf((float)ar * 0.125f) * 2.8853900817779268f;
        rl = fminf(rl, 15.0f);
        bucket = rb + (int)rl;
    }
    #pragma unroll
    for (int h = 0; h < cH; h++)
        bt[h * 4096 + 2048 + delta] = rel_bias[bucket * cH + h];
}

// ---------------------------------------------------------------------------
// Kernel 2a: hidden fp32 -> bf16, flat. 8 elems/thread.
// ---------------------------------------------------------------------------
__global__ __launch_bounds__(256) void conv_hidden_kernel(
    const float* __restrict__ h, short* __restrict__ hbf) {
    int t = blockIdx.x * 256 + threadIdx.x;
    const float4* src = (const float4*)h;
    float4 a = src[2 * t], b = src[2 * t + 1];
    BfPack p;
    p.s[0] = f2bf(a.x); p.s[1] = f2bf(a.y); p.s[2] = f2bf(a.z); p.s[3] = f2bf(a.w);
    p.s[4] = f2bf(b.x); p.s[5] = f2bf(b.y); p.s[6] = f2bf(b.z); p.s[7] = f2bf(b.w);
    ((bf16x8*)hbf)[t] = p.v;
}

// ---------------------------------------------------------------------------
// Kernel 2b: weights fp32 [K][N] -> bf16 TRANSPOSED Wt[z][N][K].
// z: 0=Wq (x0.125 folded in), 1=Wk, 2=Wv, 3=Wo. 64x64 tiles via LDS.
// ---------------------------------------------------------------------------
__global__ __launch_bounds__(256) void conv_wt_kernel(
    const float* __restrict__ Wq, const float* __restrict__ Wk,
    const float* __restrict__ Wv, const float* __restrict__ Wo,
    short* __restrict__ Wt) {
    const int z = blockIdx.z;
    const float* W = (z == 0) ? Wq : (z == 1) ? Wk : (z == 2) ? Wv : Wo;
    const float scale = (z == 0) ? 0.125f : 1.0f;
    const int n0 = blockIdx.x * 64, k0 = blockIdx.y * 64;
    __shared__ short sW[64][72];     // [k][n]
    const int t = threadIdx.x;
    const int r = t >> 2, c4 = (t & 3) * 16;
    {
        const float* src = W + (size_t)(k0 + r) * cM + n0 + c4;
        BfPack p[2];
        #pragma unroll
        for (int q = 0; q < 2; q++) {
            float4 x = ((const float4*)src)[2 * q];
            float4 y = ((const float4*)src)[2 * q + 1];
            p[q].s[0] = f2bf(x.x * scale); p[q].s[1] = f2bf(x.y * scale);
            p[q].s[2] = f2bf(x.z * scale); p[q].s[3] = f2bf(x.w * scale);
            p[q].s[4] = f2bf(y.x * scale); p[q].s[5] = f2bf(y.y * scale);
            p[q].s[6] = f2bf(y.z * scale); p[q].s[7] = f2bf(y.w * scale);
        }
        *(bf16x8*)&sW[r][c4] = p[0].v;
        *(bf16x8*)&sW[r][c4 + 8] = p[1].v;
    }
    __syncthreads();
    const int n = t >> 2, kc = (t & 3) * 16;
    BfPack o0, o1;
    #pragma unroll
    for (int j = 0; j < 8; j++) o0.s[j] = sW[kc + j][n];
    #pragma unroll
    for (int j = 0; j < 8; j++) o1.s[j] = sW[kc + 8 + j][n];
    short* dst = Wt + (size_t)z * cM * cIn + (size_t)(n0 + n) * cIn + k0 + kc;
    *(bf16x8*)dst = o0.v;
    *(bf16x8*)(dst + 8) = o1.v;
}

// ---------------------------------------------------------------------------
// Kernel 3: m97-style 128x128 GEMM for QKV. A=hbf[4096][1024], Bt=Wt[z][N][K].
// z=0 -> Q row-major, z=1 -> K row-major, z=2 -> V^T [b][h][d][s] via
// per-wave LDS quadrant transpose.
// ---------------------------------------------------------------------------
__global__ __launch_bounds__(256) void gemm_qkv_kernel(
    const short* __restrict__ hbf, const short* __restrict__ Wt,
    short* __restrict__ Qrm, short* __restrict__ Krm, short* __restrict__ VT) {
    const int z = blockIdx.z;
    const short* Bt = Wt + (size_t)z * cM * cIn;
    const int m0 = blockIdx.y * 128, c0 = blockIdx.x * 128;

    __shared__ short smem[8192];         // A [128][32] then B [128][32]
    short* sA = smem;
    short* sB = smem + 4096;

    const int tid = threadIdx.x, w = tid >> 6, l = tid & 63;
    const int m16 = l & 15, g = l >> 4;
    const int srow = l >> 2, scol = (l & 3) * 8;   // staging: 16 rows x 4 chunks

    f32x4 acc[4][4] = {};
    const int mq = (w & 1) * 64, nq = (w >> 1) * 64;

    for (int k0 = 0; k0 < cIn; k0 += 32) {
        __syncthreads();
        async16(hbf + (size_t)(m0 + w * 16 + srow) * cIn + k0 + scol,
                sA + w * 512 + l * 8);
        async16(hbf + (size_t)(m0 + 64 + w * 16 + srow) * cIn + k0 + scol,
                sA + 2048 + w * 512 + l * 8);
        async16(Bt + (size_t)(c0 + w * 16 + srow) * cIn + k0 + scol,
                sB + w * 512 + l * 8);
        async16(Bt + (size_t)(c0 + 64 + w * 16 + srow) * cIn + k0 + scol,
                sB + 2048 + w * 512 + l * 8);
        __syncthreads();
        bf16x8 af[4], bf[4];
        #pragma unroll
        for (int i = 0; i < 4; i++)
            af[i] = *(const bf16x8*)(sA + (mq + i * 16 + m16) * 32 + g * 8);
        #pragma unroll
        for (int j = 0; j < 4; j++)
            bf[j] = *(const bf16x8*)(sB + (nq + j * 16 + m16) * 32 + g * 8);
        #pragma unroll
        for (int i = 0; i < 4; i++)
            #pragma unroll
            for (int j = 0; j < 4; j++)
                acc[i][j] = mfma16(af[i], bf[j], acc[i][j]);
    }

    if (z <= 1) {
        short* dst = (z == 0) ? Qrm : Krm;
        #pragma unroll
        for (int i = 0; i < 4; i++)
            #pragma unroll
            for (int j = 0; j < 4; j++)
                #pragma unroll
                for (int r = 0; r < 4; r++)
                    dst[(size_t)(m0 + mq + i * 16 + g * 4 + r) * cM +
                        c0 + nq + j * 16 + m16] = f2bf(acc[i][j][r]);
    } else {
        // V^T: per-wave 16-col chunks through LDS.  sTw: [n_local 16][m_local 64]
        __syncthreads();
        short* sTw = smem + w * 1152;    // 16*72 shorts per wave
        #pragma unroll
        for (int j = 0; j < 4; j++) {
            #pragma unroll
            for (int i = 0; i < 4; i++)
                #pragma unroll
                for (int r = 0; r < 4; r++)
                    sTw[m16 * 72 + i * 16 + g * 4 + r] = f2bf(acc[i][j][r]);
            __builtin_amdgcn_wave_barrier();
            const int dl = l >> 2, ck = (l & 3) * 16;
            bf16x8 v0 = *(const bf16x8*)&sTw[dl * 72 + ck];
            bf16x8 v1 = *(const bf16x8*)&sTw[dl * 72 + ck + 8];
            const int col = c0 + nq + j * 16 + dl;      // h*64 + d
            const int hh = col >> 6, dd = col & 63;
            const int mrow = m0 + mq;
            const int bb = mrow >> 11, sbase = (mrow & 2047) + ck;
            short* dp = VT + (((size_t)bb * cH + hh) * cD + dd) * cS + sbase;
            *(bf16x8*)dp = v0;
            *(bf16x8*)(dp + 8) = v1;
            __builtin_amdgcn_wave_barrier();
        }
    }
}

// ---------------------------------------------------------------------------
// Kernel 4: flash attention (LDS-staged K/V tiles, barrier-per-tile only).
// Q,K row-major [b*S][1024]; V^T [b][h][d][s].
// ---------------------------------------------------------------------------
__global__ __launch_bounds__(256) void attn_kernel(
    const short* __restrict__ Qrm, const short* __restrict__ Krm,
    const short* __restrict__ VT, const int* __restrict__ mask,
    const float* __restrict__ bias_t, short* __restrict__ ctx) {
    const int b = blockIdx.z, h = blockIdx.y;
    const int q0 = blockIdx.x * 64;
    const short* VTp = VT + ((size_t)b * cH + h) * cS * cD;   // [d][s]
    const int* mp = mask + b * cS;
    const float* bh = bias_t + h * 4096 + 2048;

    const int tid = threadIdx.x;
    const int wave = tid >> 6, lane = tid & 63;
    const int m16 = lane & 15, g = lane >> 4;

    __shared__ short Kt[64][72];       // [key][d] pad8
    __shared__ short Vt[64][72];       // [d][key] pad8
    __shared__ short Ps[4][16][72];    // per-wave P in A-layout

    const int qrow16 = q0 + wave * 16 + m16;
    const short* qb = Qrm + (size_t)(b * cS + qrow16) * cM + h * cD;
    bf16x8 qf0 = *(const bf16x8*)(qb + g * 8);
    bf16x8 qf1 = *(const bf16x8*)(qb + 32 + g * 8);

    f32x4 o0 = {}, o1 = {}, o2 = {}, o3 = {};
    float lsum[4] = {0.f, 0.f, 0.f, 0.f};
    int qr[4];
    #pragma unroll
    for (int r = 0; r < 4; r++) qr[r] = q0 + wave * 16 + g * 4 + r;

    const int srow = tid >> 3;               // 0..31
    const int scol = (tid & 7) << 3;         // 0,8,..,56
    const short* kbase = Krm + (size_t)b * cS * cM + h * cD;

    for (int kt = 0; kt < cS; kt += 64) {
        __syncthreads();
        *(bf16x8*)&Kt[srow][scol] =
            *(const bf16x8*)(kbase + (size_t)(kt + srow) * cM + scol);
        *(bf16x8*)&Kt[srow + 32][scol] =
            *(const bf16x8*)(kbase + (size_t)(kt + srow + 32) * cM + scol);
        *(bf16x8*)&Vt[srow][scol] =
            *(const bf16x8*)(VTp + (size_t)srow * cS + kt + scol);
        *(bf16x8*)&Vt[srow + 32][scol] =
            *(const bf16x8*)(VTp + (size_t)(srow + 32) * cS + kt + scol);
        __syncthreads();

        f32x4 s[4];
        #pragma unroll
        for (int st = 0; st < 4; st++) {
            bf16x8 klo = *(const bf16x8*)&Kt[st * 16 + m16][g * 8];
            bf16x8 khi = *(const bf16x8*)&Kt[st * 16 + m16][32 + g * 8];
            f32x4 t = {};
            t = mfma16(qf0, klo, t);
            t = mfma16(qf1, khi, t);
            s[st] = t;
        }

        #pragma unroll
        for (int st = 0; st < 4; st++) {
            const int key = kt + st * 16 + m16;
            const float madd = (1.0f - (float)mp[key]) * -3.0e38f;
            const float* bk = bh + key;
            #pragma unroll
            for (int r = 0; r < 4; r++) {
                float p = __expf(s[st][r] + bk[-qr[r]] + madd);
                lsum[r] += p;
                Ps[wave][g * 4 + r][st * 16 + m16] = f2bf(p);
            }
        }
        __builtin_amdgcn_wave_barrier();
        bf16x8 pf0 = *(const bf16x8*)&Ps[wave][m16][g * 8];
        bf16x8 pf1 = *(const bf16x8*)&Ps[wave][m16][32 + g * 8];
        __builtin_amdgcn_wave_barrier();

        #pragma unroll
        for (int nt = 0; nt < 4; nt++) {
            bf16x8 vlo = *(const bf16x8*)&Vt[nt * 16 + m16][g * 8];
            bf16x8 vhi = *(const bf16x8*)&Vt[nt * 16 + m16][32 + g * 8];
            f32x4* o = (nt == 0) ? &o0 : (nt == 1) ? &o1 : (nt == 2) ? &o2 : &o3;
            *o = mfma16(pf0, vlo, *o);
            *o = mfma16(pf1, vhi, *o);
        }
    }

    #pragma unroll
    for (int off = 1; off < 16; off <<= 1) {
        #pragma unroll
        for (int r = 0; r < 4; r++) lsum[r] += __shfl_xor(lsum[r], off, 64);
    }
    #pragma unroll
    for (int r = 0; r < 4; r++) {
        float inv = 1.0f / lsum[r];
        size_t base = ((size_t)b * cS + qr[r]) * cM + h * cD;
        ctx[base +  0 + m16] = f2bf(o0[r] * inv);
        ctx[base + 16 + m16] = f2bf(o1[r] * inv);
        ctx[base + 32 + m16] = f2bf(o2[r] * inv);
        ctx[base + 48 + m16] = f2bf(o3[r] * inv);
    }
}

// ---------------------------------------------------------------------------
// Kernel 5: m97-style 128x128 GEMM, out fp32 = ctx(bf16) @ WoT
// ---------------------------------------------------------------------------
__global__ __launch_bounds__(256) void gemm_o_kernel(
    const short* __restrict__ ctx, const short* __restrict__ WoT,
    float* __restrict__ out) {
    const int m0 = blockIdx.y * 128, c0 = blockIdx.x * 128;
    __shared__ short smem[8192];
    short* sA = smem;
    short* sB = smem + 4096;
    const int tid = threadIdx.x, w = tid >> 6, l = tid & 63;
    const int m16 = l & 15, g = l >> 4;
    const int srow = l >> 2, scol = (l & 3) * 8;
    f32x4 acc[4][4] = {};
    const int mq = (w & 1) * 64, nq = (w >> 1) * 64;

    for (int k0 = 0; k0 < cIn; k0 += 32) {
        __syncthreads();
        async16(ctx + (size_t)(m0 + w * 16 + srow) * cIn + k0 + scol,
                sA + w * 512 + l * 8);
        async16(ctx + (size_t)(m0 + 64 + w * 16 + srow) * cIn + k0 + scol,
                sA + 2048 + w * 512 + l * 8);
        async16(WoT + (size_t)(c0 + w * 16 + srow) * cIn + k0 + scol,
                sB + w * 512 + l * 8);
        async16(WoT + (size_t)(c0 + 64 + w * 16 + srow) * cIn + k0 + scol,
                sB + 2048 + w * 512 + l * 8);
        __syncthreads();
        bf16x8 af[4], bf[4];
        #pragma unroll
        for (int i = 0; i < 4; i++)
            af[i] = *(const bf16x8*)(sA + (mq + i * 16 + m16) * 32 + g * 8);
        #pragma unroll
        for (int j = 0; j < 4; j++)
            bf[j] = *(const bf16x8*)(sB + (nq + j * 16 + m16) * 32 + g * 8);
        #pragma unroll
        for (int i = 0; i < 4; i++)
            #pragma unroll
            for (int j = 0; j < 4; j++)
                acc[i][j] = mfma16(af[i], bf[j], acc[i][j]);
    }
    #pragma unroll
    for (int i = 0; i < 4; i++)
        #pragma unroll
        for (int j = 0; j < 4; j++)
            #pragma unroll
            for (int r = 0; r < 4; r++)
                out[(size_t)(m0 + mq + i * 16 + g * 4 + r) * cM +
                    c0 + nq + j * 16 + m16] = acc[i][j][r];
}

extern "C" void kernel_launch(void* const* d_in, const int* in_sizes, int n_in,
                              void* d_out, int out_size, void* d_ws, size_t ws_size,
                              hipStream_t stream) {
    const float* hidden   = (const float*)d_in[0];
    const int*   mask     = (const int*)d_in[1];
    const float* Wq       = (const float*)d_in[2];
    const float* Wk       = (const float*)d_in[3];
    const float* Wv       = (const float*)d_in[4];
    const float* Wo       = (const float*)d_in[5];
    const float* rel_bias = (const float*)d_in[6];
    float* out = (float*)d_out;

    // ws layout (shorts): hbf/ctx 4M | Wt 4x1M | Q 4M | K 4M | VT 4M | bias 64K f32
    // hbf slot is reused as ctx (hbf dead after gemm_qkv; ctx written by attn).
    short* hbf_ctx = (short*)d_ws;
    short* Wt  = hbf_ctx + (size_t)4 * 1024 * 1024;
    short* Qrm = Wt  + (size_t)4 * 1024 * 1024;
    short* Krm = Qrm + (size_t)4 * 1024 * 1024;
    short* VT  = Krm + (size_t)4 * 1024 * 1024;
    float* bias_t = (float*)(VT + (size_t)4 * 1024 * 1024);

    bias_table_kernel<<<16, 256, 0, stream>>>(rel_bias, bias_t);
    conv_hidden_kernel<<<2048, 256, 0, stream>>>(hidden, hbf_ctx);
    conv_wt_kernel<<<dim3(16, 16, 4), 256, 0, stream>>>(Wq, Wk, Wv, Wo, Wt);
    gemm_qkv_kernel<<<dim3(8, 32, 3), 256, 0, stream>>>(hbf_ctx, Wt, Qrm, Krm, VT);
    attn_kernel<<<dim3(32, cH, cB), 256, 0, stream>>>(Qrm, Krm, VT, mask, bias_t,
                                                      hbf_ctx);
    gemm_o_kernel<<<dim3(8, 32), 256, 0, stream>>>(hbf_ctx, Wt + (size_t)3 * 1024 * 1024,
                                                   out);
}

// Round 6
// 216.309 us; speedup vs baseline: 2.8754x; 1.1483x over previous
//
#include <hip/hip_runtime.h>
#include <hip/hip_bf16.h>
#include <math.h>

typedef __attribute__((ext_vector_type(8))) short bf16x8;
typedef __attribute__((ext_vector_type(4))) short s16x4;
typedef __attribute__((ext_vector_type(4))) float f32x4;

constexpr int cB = 2, cS = 2048, cH = 16, cD = 64, cIn = 1024, cM = 1024;

union BfPack { bf16x8 v; short s[8]; };
union BfPack4 { s16x4 v; short s[4]; };

__device__ __forceinline__ short f2bf(float f) {
    union { float f; unsigned u; } v; v.f = f;
    unsigned r = v.u + 0x7fffu + ((v.u >> 16) & 1u);   // round-to-nearest-even
    return (short)(r >> 16);
}

__device__ __forceinline__ f32x4 mfma16(bf16x8 a, bf16x8 b, f32x4 c) {
    return __builtin_amdgcn_mfma_f32_16x16x32_bf16(a, b, c, 0, 0, 0);
}

__device__ __forceinline__ void async16(const short* g, short* l) {
    __builtin_amdgcn_global_load_lds(
        (const __attribute__((address_space(1))) unsigned*)(uintptr_t)g,
        (__attribute__((address_space(3))) unsigned*)(uintptr_t)l, 16, 0, 0);
}

// ---------------------------------------------------------------------------
// Kernel 1: bias table bt[h][2048+delta] (transposed) + maskadd[b][key]
// ---------------------------------------------------------------------------
__global__ void bias_table_kernel(const float* __restrict__ rel_bias,
                                  const int* __restrict__ mask,
                                  float* __restrict__ bt,
                                  float* __restrict__ maskadd) {
    int idx = blockIdx.x * blockDim.x + threadIdx.x;
    if (idx < 4096) maskadd[idx] = (1.0f - (float)mask[idx]) * -3.0e38f;
    if (idx >= 4095) return;
    int delta = idx - 2047;
    int rb = (delta > 0) ? 16 : 0;
    int ar = delta < 0 ? -delta : delta;
    int bucket;
    if (ar < 8) {
        bucket = rb + ar;
    } else {
        float rl = 8.0f + logf((float)ar * 0.125f) * 2.8853900817779268f;
        rl = fminf(rl, 15.0f);
        bucket = rb + (int)rl;
    }
    #pragma unroll
    for (int h = 0; h < cH; h++)
        bt[h * 4096 + 2048 + delta] = rel_bias[bucket * cH + h];
}

// ---------------------------------------------------------------------------
// Kernel 2a: hidden fp32 -> bf16, flat.
// ---------------------------------------------------------------------------
__global__ __launch_bounds__(256) void conv_hidden_kernel(
    const float* __restrict__ h, short* __restrict__ hbf) {
    int t = blockIdx.x * 256 + threadIdx.x;
    const float4* src = (const float4*)h;
    float4 a = src[2 * t], b = src[2 * t + 1];
    BfPack p;
    p.s[0] = f2bf(a.x); p.s[1] = f2bf(a.y); p.s[2] = f2bf(a.z); p.s[3] = f2bf(a.w);
    p.s[4] = f2bf(b.x); p.s[5] = f2bf(b.y); p.s[6] = f2bf(b.z); p.s[7] = f2bf(b.w);
    ((bf16x8*)hbf)[t] = p.v;
}

// ---------------------------------------------------------------------------
// Kernel 2b: weights fp32 [K][N] -> bf16 TRANSPOSED Wt[z][N][K].
// ---------------------------------------------------------------------------
__global__ __launch_bounds__(256) void conv_wt_kernel(
    const float* __restrict__ Wq, const float* __restrict__ Wk,
    const float* __restrict__ Wv, const float* __restrict__ Wo,
    short* __restrict__ Wt) {
    const int z = blockIdx.z;
    const float* W = (z == 0) ? Wq : (z == 1) ? Wk : (z == 2) ? Wv : Wo;
    const float scale = (z == 0) ? 0.125f : 1.0f;
    const int n0 = blockIdx.x * 64, k0 = blockIdx.y * 64;
    __shared__ short sW[64][72];     // [k][n]
    const int t = threadIdx.x;
    const int r = t >> 2, c4 = (t & 3) * 16;
    {
        const float* src = W + (size_t)(k0 + r) * cM + n0 + c4;
        BfPack p[2];
        #pragma unroll
        for (int q = 0; q < 2; q++) {
            float4 x = ((const float4*)src)[2 * q];
            float4 y = ((const float4*)src)[2 * q + 1];
            p[q].s[0] = f2bf(x.x * scale); p[q].s[1] = f2bf(x.y * scale);
            p[q].s[2] = f2bf(x.z * scale); p[q].s[3] = f2bf(x.w * scale);
            p[q].s[4] = f2bf(y.x * scale); p[q].s[5] = f2bf(y.y * scale);
            p[q].s[6] = f2bf(y.z * scale); p[q].s[7] = f2bf(y.w * scale);
        }
        *(bf16x8*)&sW[r][c4] = p[0].v;
        *(bf16x8*)&sW[r][c4 + 8] = p[1].v;
    }
    __syncthreads();
    const int n = t >> 2, kc = (t & 3) * 16;
    BfPack o0, o1;
    #pragma unroll
    for (int j = 0; j < 8; j++) o0.s[j] = sW[kc + j][n];
    #pragma unroll
    for (int j = 0; j < 8; j++) o1.s[j] = sW[kc + 8 + j][n];
    short* dst = Wt + (size_t)z * cM * cIn + (size_t)(n0 + n) * cIn + k0 + kc;
    *(bf16x8*)dst = o0.v;
    *(bf16x8*)(dst + 8) = o1.v;
}

// ---------------------------------------------------------------------------
// GEMM core: stages A[128][32], B[128][32] via global_load_lds, 16 MFMAs/step.
// SWAP=false: D[m=A-row][n=B-row].  SWAP=true: D[m=B-row][n=A-row].
// ---------------------------------------------------------------------------
template <bool SWAP>
__device__ __forceinline__ void gemm_core(
    const short* __restrict__ A, const short* __restrict__ Bt,
    short* smem, int m0, int c0, int tid, f32x4 (&acc)[4][4]) {
    short* sA = smem;
    short* sB = smem + 4096;
    const int w = tid >> 6, l = tid & 63;
    const int m16 = l & 15, g = l >> 4;
    const int srow = l >> 2, scol = (l & 3) * 8;
    const int mq = (w & 1) * 64, nq = (w >> 1) * 64;

    for (int k0 = 0; k0 < cIn; k0 += 32) {
        __syncthreads();
        async16(A + (size_t)(m0 + w * 16 + srow) * cIn + k0 + scol,
                sA + w * 512 + l * 8);
        async16(A + (size_t)(m0 + 64 + w * 16 + srow) * cIn + k0 + scol,
                sA + 2048 + w * 512 + l * 8);
        async16(Bt + (size_t)(c0 + w * 16 + srow) * cIn + k0 + scol,
                sB + w * 512 + l * 8);
        async16(Bt + (size_t)(c0 + 64 + w * 16 + srow) * cIn + k0 + scol,
                sB + 2048 + w * 512 + l * 8);
        __syncthreads();
        bf16x8 af[4], bf[4];
        #pragma unroll
        for (int i = 0; i < 4; i++)
            af[i] = *(const bf16x8*)(sA + (mq + i * 16 + m16) * 32 + g * 8);
        #pragma unroll
        for (int j = 0; j < 4; j++)
            bf[j] = *(const bf16x8*)(sB + (nq + j * 16 + m16) * 32 + g * 8);
        #pragma unroll
        for (int i = 0; i < 4; i++)
            #pragma unroll
            for (int j = 0; j < 4; j++)
                acc[i][j] = SWAP ? mfma16(bf[j], af[i], acc[i][j])
                                 : mfma16(af[i], bf[j], acc[i][j]);
    }
}

// ---------------------------------------------------------------------------
// Kernel 3: QKV GEMM. z=0 Q row-major, z=1 K row-major,
// z=2 V^T [b][h][d][s] produced DIRECTLY via operand-swapped MFMA.
// ---------------------------------------------------------------------------
__global__ __launch_bounds__(256) void gemm_qkv_kernel(
    const short* __restrict__ hbf, const short* __restrict__ Wt,
    short* __restrict__ Qrm, short* __restrict__ Krm, short* __restrict__ VT) {
    const int z = blockIdx.z;
    const short* Bt = Wt + (size_t)z * cM * cIn;
    const int m0 = blockIdx.y * 128, c0 = blockIdx.x * 128;
    __shared__ short smem[8192];
    const int tid = threadIdx.x, w = tid >> 6, l = tid & 63;
    const int m16 = l & 15, g = l >> 4;
    const int mq = (w & 1) * 64, nq = (w >> 1) * 64;
    f32x4 acc[4][4] = {};

    if (z <= 1) {
        gemm_core<false>(hbf, Bt, smem, m0, c0, tid, acc);
        short* dst = (z == 0) ? Qrm : Krm;
        #pragma unroll
        for (int i = 0; i < 4; i++)
            #pragma unroll
            for (int j = 0; j < 4; j++)
                #pragma unroll
                for (int r = 0; r < 4; r++)
                    dst[(size_t)(m0 + mq + i * 16 + g * 4 + r) * cM +
                        c0 + nq + j * 16 + m16] = f2bf(acc[i][j][r]);
    } else {
        gemm_core<true>(hbf, Bt, smem, m0, c0, tid, acc);
        // D[m=weight col (h*64+d)][n=hidden row (b*S+s)]; lanes carry s.
        #pragma unroll
        for (int i = 0; i < 4; i++) {
            const int srow_g = m0 + mq + i * 16 + m16;   // b*S + s
            const int bb = srow_g >> 11, ss = srow_g & 2047;
            #pragma unroll
            for (int j = 0; j < 4; j++)
                #pragma unroll
                for (int r = 0; r < 4; r++) {
                    const int wcol = c0 + nq + j * 16 + g * 4 + r;  // h*64+d
                    VT[(((size_t)bb * cH + (wcol >> 6)) * cD + (wcol & 63)) * cS
                       + ss] = f2bf(acc[i][j][r]);
                }
        }
    }
}

// ---------------------------------------------------------------------------
// Kernel 4: flash attention, register-resident P (no LDS round trip).
// S^T via mfma(K, Q): q on lanes, keys on regs. Key permutation kappa =
// (st&1)*32 + g*8 + (st>>1)*4 + r applied to BOTH P's k-index (register
// packing) and V's LDS rows -> P fragments come straight from registers.
// ---------------------------------------------------------------------------
__global__ __launch_bounds__(256) void attn_kernel(
    const short* __restrict__ Qrm, const short* __restrict__ Krm,
    const short* __restrict__ VT, const float* __restrict__ maskadd,
    const float* __restrict__ bias_t, short* __restrict__ ctx) {
    const int b = blockIdx.z, h = blockIdx.y;
    const int q0 = blockIdx.x * 64;
    const short* VTp = VT + ((size_t)b * cH + h) * cS * cD;   // [d][s]
    const float* bh = bias_t + h * 4096 + 2048;
    const float* mp = maskadd + b * cS;

    const int tid = threadIdx.x;
    const int wave = tid >> 6, lane = tid & 63;
    const int m16 = lane & 15, g = lane >> 4;

    __shared__ short Kt[64][72];       // [key][d]
    __shared__ short Vt[64][72];       // [d][kappa]

    const int q = q0 + wave * 16 + m16;          // this thread's single q row
    const short* qb = Qrm + (size_t)(b * cS + q) * cM + h * cD;
    bf16x8 qf0 = *(const bf16x8*)(qb + g * 8);
    bf16x8 qf1 = *(const bf16x8*)(qb + 32 + g * 8);

    f32x4 o[4] = {};
    float lsum = 0.f;

    const int srow = tid >> 3;               // 0..31
    const int scol = (tid & 7) << 3;         // 0,8,..,56
    // kappa base for staged V chunk (keys scol..scol+7):
    const int kb = ((scol >> 4) & 1) * 32 + ((scol >> 3) & 1) * 16 +
                   ((scol >> 5) & 1) * 4;
    const short* kbase = Krm + (size_t)b * cS * cM + h * cD;

    for (int kt = 0; kt < cS; kt += 64) {
        __syncthreads();
        *(bf16x8*)&Kt[srow][scol] =
            *(const bf16x8*)(kbase + (size_t)(kt + srow) * cM + scol);
        *(bf16x8*)&Kt[srow + 32][scol] =
            *(const bf16x8*)(kbase + (size_t)(kt + srow + 32) * cM + scol);
        {
            BfPack v0, v1;
            v0.v = *(const bf16x8*)(VTp + (size_t)srow * cS + kt + scol);
            v1.v = *(const bf16x8*)(VTp + (size_t)(srow + 32) * cS + kt + scol);
            BfPack4 a, bb2, c, d;
            #pragma unroll
            for (int i = 0; i < 4; i++) { a.s[i] = v0.s[i]; bb2.s[i] = v0.s[4 + i]; }
            #pragma unroll
            for (int i = 0; i < 4; i++) { c.s[i] = v1.s[i]; d.s[i] = v1.s[4 + i]; }
            *(s16x4*)&Vt[srow][kb]          = a.v;
            *(s16x4*)&Vt[srow][kb + 8]      = bb2.v;
            *(s16x4*)&Vt[srow + 32][kb]     = c.v;
            *(s16x4*)&Vt[srow + 32][kb + 8] = d.v;
        }
        __syncthreads();

        // ---- S^T: A=K (keys on regs), B=Q (q on lanes). 8 MFMAs.
        f32x4 s[4];
        #pragma unroll
        for (int st = 0; st < 4; st++) {
            bf16x8 klo = *(const bf16x8*)&Kt[st * 16 + m16][g * 8];
            bf16x8 khi = *(const bf16x8*)&Kt[st * 16 + m16][32 + g * 8];
            f32x4 t = {};
            t = mfma16(klo, qf0, t);
            t = mfma16(khi, qf1, t);
            s[st] = t;
        }

        // ---- softmax numerator; pack P fragments in registers
        BfPack pp[2];
        #pragma unroll
        for (int st = 0; st < 4; st++) {
            const int keybase = kt + st * 16 + g * 4;
            #pragma unroll
            for (int r = 0; r < 2; r++) {   // pairs for packed cvt
                float x0 = s[st][2 * r] + bh[keybase + 2 * r - q] + mp[keybase + 2 * r];
                float x1 = s[st][2 * r + 1] + bh[keybase + 2 * r + 1 - q] + mp[keybase + 2 * r + 1];
                float p0 = __expf(x0), p1 = __expf(x1);
                lsum += p0 + p1;
                __hip_bfloat162 h2 = __float22bfloat162_rn(float2{p0, p1});
                short2 sp = *(short2*)&h2;
                pp[st & 1].s[(st >> 1) * 4 + 2 * r]     = sp.x;
                pp[st & 1].s[(st >> 1) * 4 + 2 * r + 1] = sp.y;
            }
        }

        // ---- O^T = mfma(A=V^T, B=P): 8 MFMAs, P straight from registers
        #pragma unroll
        for (int nt = 0; nt < 4; nt++) {
            bf16x8 vlo = *(const bf16x8*)&Vt[nt * 16 + m16][g * 8];
            bf16x8 vhi = *(const bf16x8*)&Vt[nt * 16 + m16][32 + g * 8];
            o[nt] = mfma16(vlo, pp[0].v, o[nt]);
            o[nt] = mfma16(vhi, pp[1].v, o[nt]);
        }
    }

    // ---- row denominator: sum across the 4 g-groups (bits 4,5 of lane)
    lsum += __shfl_xor(lsum, 16, 64);
    lsum += __shfl_xor(lsum, 32, 64);
    const float inv = 1.0f / lsum;

    // ---- write ctx[b*S+q][h*64 + d], d = nt*16 + g*4 + r (b64 per nt)
    short* cb = ctx + ((size_t)b * cS + q) * cM + h * cD;
    #pragma unroll
    for (int nt = 0; nt < 4; nt++) {
        BfPack4 pk;
        #pragma unroll
        for (int r = 0; r < 4; r++) pk.s[r] = f2bf(o[nt][r] * inv);
        *(s16x4*)(cb + nt * 16 + g * 4) = pk.v;
    }
}

// ---------------------------------------------------------------------------
// Kernel 5: out fp32 = ctx(bf16) @ WoT
// ---------------------------------------------------------------------------
__global__ __launch_bounds__(256) void gemm_o_kernel(
    const short* __restrict__ ctx, const short* __restrict__ WoT,
    float* __restrict__ out) {
    const int m0 = blockIdx.y * 128, c0 = blockIdx.x * 128;
    __shared__ short smem[8192];
    const int tid = threadIdx.x, w = tid >> 6, l = tid & 63;
    const int m16 = l & 15, g = l >> 4;
    const int mq = (w & 1) * 64, nq = (w >> 1) * 64;
    f32x4 acc[4][4] = {};
    gemm_core<false>(ctx, WoT, smem, m0, c0, tid, acc);
    #pragma unroll
    for (int i = 0; i < 4; i++)
        #pragma unroll
        for (int j = 0; j < 4; j++)
            #pragma unroll
            for (int r = 0; r < 4; r++)
                out[(size_t)(m0 + mq + i * 16 + g * 4 + r) * cM +
                    c0 + nq + j * 16 + m16] = acc[i][j][r];
}

extern "C" void kernel_launch(void* const* d_in, const int* in_sizes, int n_in,
                              void* d_out, int out_size, void* d_ws, size_t ws_size,
                              hipStream_t stream) {
    const float* hidden   = (const float*)d_in[0];
    const int*   mask     = (const int*)d_in[1];
    const float* Wq       = (const float*)d_in[2];
    const float* Wk       = (const float*)d_in[3];
    const float* Wv       = (const float*)d_in[4];
    const float* Wo       = (const float*)d_in[5];
    const float* rel_bias = (const float*)d_in[6];
    float* out = (float*)d_out;

    // ws (shorts): hbf/ctx 4M | Wt 4x1M | Q 4M | K 4M | VT 4M | bias 256KB | mask 16KB
    short* hbf_ctx = (short*)d_ws;
    short* Wt  = hbf_ctx + (size_t)4 * 1024 * 1024;
    short* Qrm = Wt  + (size_t)4 * 1024 * 1024;
    short* Krm = Qrm + (size_t)4 * 1024 * 1024;
    short* VT  = Krm + (size_t)4 * 1024 * 1024;
    float* bias_t  = (float*)(VT + (size_t)4 * 1024 * 1024);
    float* maskf   = bias_t + 16 * 4096;

    bias_table_kernel<<<16, 256, 0, stream>>>(rel_bias, mask, bias_t, maskf);
    conv_hidden_kernel<<<2048, 256, 0, stream>>>(hidden, hbf_ctx);
    conv_wt_kernel<<<dim3(16, 16, 4), 256, 0, stream>>>(Wq, Wk, Wv, Wo, Wt);
    gemm_qkv_kernel<<<dim3(8, 32, 3), 256, 0, stream>>>(hbf_ctx, Wt, Qrm, Krm, VT);
    attn_kernel<<<dim3(32, cH, cB), 256, 0, stream>>>(Qrm, Krm, VT, maskf, bias_t,
                                                      hbf_ctx);
    gemm_o_kernel<<<dim3(8, 32), 256, 0, stream>>>(hbf_ctx, Wt + (size_t)3 * 1024 * 1024,
                                                   out);
}

// Round 8
// 213.752 us; speedup vs baseline: 2.9098x; 1.0120x over previous
//
#include <hip/hip_runtime.h>
#include <hip/hip_bf16.h>
#include <math.h>

typedef __attribute__((ext_vector_type(8))) short bf16x8;
typedef __attribute__((ext_vector_type(4))) short s16x4;
typedef __attribute__((ext_vector_type(4))) float f32x4;

constexpr int cB = 2, cS = 2048, cH = 16, cD = 64, cIn = 1024, cM = 1024;
constexpr float cLog2e = 1.4426950408889634f;

union BfPack { bf16x8 v; short s[8]; };
union BfPack4 { s16x4 v; short s[4]; };

__device__ __forceinline__ short f2bf(float f) {
    union { float f; unsigned u; } v; v.f = f;
    unsigned r = v.u + 0x7fffu + ((v.u >> 16) & 1u);   // round-to-nearest-even
    return (short)(r >> 16);
}

__device__ __forceinline__ f32x4 mfma16(bf16x8 a, bf16x8 b, f32x4 c) {
    return __builtin_amdgcn_mfma_f32_16x16x32_bf16(a, b, c, 0, 0, 0);
}

__device__ __forceinline__ void async16(const short* g, short* l) {
    __builtin_amdgcn_global_load_lds(
        (const __attribute__((address_space(1))) unsigned*)(uintptr_t)g,
        (__attribute__((address_space(3))) unsigned*)(uintptr_t)l, 16, 0, 0);
}

// ---------------------------------------------------------------------------
// Kernel 1: bias table bt[h][2048+delta] PRE-SCALED by log2(e) (for exp2),
// plus maskadd[b][key] (huge negative where masked; exp2 -> 0).
// ---------------------------------------------------------------------------
__global__ void bias_table_kernel(const float* __restrict__ rel_bias,
                                  const int* __restrict__ mask,
                                  float* __restrict__ bt,
                                  float* __restrict__ maskadd) {
    int idx = blockIdx.x * blockDim.x + threadIdx.x;
    if (idx < 4096) maskadd[idx] = (1.0f - (float)mask[idx]) * -3.0e38f;
    if (idx >= 4095) return;
    int delta = idx - 2047;
    int rb = (delta > 0) ? 16 : 0;
    int ar = delta < 0 ? -delta : delta;
    int bucket;
    if (ar < 8) {
        bucket = rb + ar;
    } else {
        float rl = 8.0f + logf((float)ar * 0.125f) * 2.8853900817779268f;
        rl = fminf(rl, 15.0f);
        bucket = rb + (int)rl;
    }
    #pragma unroll
    for (int h = 0; h < cH; h++)
        bt[h * 4096 + 2048 + delta] = rel_bias[bucket * cH + h] * cLog2e;
}

// ---------------------------------------------------------------------------
// Kernel 2a: hidden fp32 -> bf16, flat.
// ---------------------------------------------------------------------------
__global__ __launch_bounds__(256) void conv_hidden_kernel(
    const float* __restrict__ h, short* __restrict__ hbf) {
    int t = blockIdx.x * 256 + threadIdx.x;
    const float4* src = (const float4*)h;
    float4 a = src[2 * t], b = src[2 * t + 1];
    BfPack p;
    p.s[0] = f2bf(a.x); p.s[1] = f2bf(a.y); p.s[2] = f2bf(a.z); p.s[3] = f2bf(a.w);
    p.s[4] = f2bf(b.x); p.s[5] = f2bf(b.y); p.s[6] = f2bf(b.z); p.s[7] = f2bf(b.w);
    ((bf16x8*)hbf)[t] = p.v;
}

// ---------------------------------------------------------------------------
// Kernel 2b: weights fp32 [K][N] -> bf16 TRANSPOSED Wt[z][N][K].
// Wq carries 0.125 * log2(e) (softmax via exp2).
// ---------------------------------------------------------------------------
__global__ __launch_bounds__(256) void conv_wt_kernel(
    const float* __restrict__ Wq, const float* __restrict__ Wk,
    const float* __restrict__ Wv, const float* __restrict__ Wo,
    short* __restrict__ Wt) {
    const int z = blockIdx.z;
    const float* W = (z == 0) ? Wq : (z == 1) ? Wk : (z == 2) ? Wv : Wo;
    const float scale = (z == 0) ? 0.125f * cLog2e : 1.0f;
    const int n0 = blockIdx.x * 64, k0 = blockIdx.y * 64;
    __shared__ short sW[64][72];     // [k][n]
    const int t = threadIdx.x;
    const int r = t >> 2, c4 = (t & 3) * 16;
    {
        const float* src = W + (size_t)(k0 + r) * cM + n0 + c4;
        BfPack p[2];
        #pragma unroll
        for (int q = 0; q < 2; q++) {
            float4 x = ((const float4*)src)[2 * q];
            float4 y = ((const float4*)src)[2 * q + 1];
            p[q].s[0] = f2bf(x.x * scale); p[q].s[1] = f2bf(x.y * scale);
            p[q].s[2] = f2bf(x.z * scale); p[q].s[3] = f2bf(x.w * scale);
            p[q].s[4] = f2bf(y.x * scale); p[q].s[5] = f2bf(y.y * scale);
            p[q].s[6] = f2bf(y.z * scale); p[q].s[7] = f2bf(y.w * scale);
        }
        *(bf16x8*)&sW[r][c4] = p[0].v;
        *(bf16x8*)&sW[r][c4 + 8] = p[1].v;
    }
    __syncthreads();
    const int n = t >> 2, kc = (t & 3) * 16;
    BfPack o0, o1;
    #pragma unroll
    for (int j = 0; j < 8; j++) o0.s[j] = sW[kc + j][n];
    #pragma unroll
    for (int j = 0; j < 8; j++) o1.s[j] = sW[kc + 8 + j][n];
    short* dst = Wt + (size_t)z * cM * cIn + (size_t)(n0 + n) * cIn + k0 + kc;
    *(bf16x8*)dst = o0.v;
    *(bf16x8*)(dst + 8) = o1.v;
}

// ---------------------------------------------------------------------------
// GEMM core (m97-style): A[128][32], B[128][32] via global_load_lds.
// ---------------------------------------------------------------------------
template <bool SWAP>
__device__ __forceinline__ void gemm_core(
    const short* __restrict__ A, const short* __restrict__ Bt,
    short* smem, int m0, int c0, int tid, f32x4 (&acc)[4][4]) {
    short* sA = smem;
    short* sB = smem + 4096;
    const int w = tid >> 6, l = tid & 63;
    const int m16 = l & 15, g = l >> 4;
    const int srow = l >> 2, scol = (l & 3) * 8;
    const int mq = (w & 1) * 64, nq = (w >> 1) * 64;

    for (int k0 = 0; k0 < cIn; k0 += 32) {
        __syncthreads();
        async16(A + (size_t)(m0 + w * 16 + srow) * cIn + k0 + scol,
                sA + w * 512 + l * 8);
        async16(A + (size_t)(m0 + 64 + w * 16 + srow) * cIn + k0 + scol,
                sA + 2048 + w * 512 + l * 8);
        async16(Bt + (size_t)(c0 + w * 16 + srow) * cIn + k0 + scol,
                sB + w * 512 + l * 8);
        async16(Bt + (size_t)(c0 + 64 + w * 16 + srow) * cIn + k0 + scol,
                sB + 2048 + w * 512 + l * 8);
        __syncthreads();
        bf16x8 af[4], bf[4];
        #pragma unroll
        for (int i = 0; i < 4; i++)
            af[i] = *(const bf16x8*)(sA + (mq + i * 16 + m16) * 32 + g * 8);
        #pragma unroll
        for (int j = 0; j < 4; j++)
            bf[j] = *(const bf16x8*)(sB + (nq + j * 16 + m16) * 32 + g * 8);
        #pragma unroll
        for (int i = 0; i < 4; i++)
            #pragma unroll
            for (int j = 0; j < 4; j++)
                acc[i][j] = SWAP ? mfma16(bf[j], af[i], acc[i][j])
                                 : mfma16(af[i], bf[j], acc[i][j]);
    }
}

// ---------------------------------------------------------------------------
// Kernel 3: QKV GEMM. z=0 Q row-major (log2e-scaled), z=1 K row-major,
// z=2 V^T [b][h][d][s] direct via operand-swapped MFMA.
// ---------------------------------------------------------------------------
__global__ __launch_bounds__(256) void gemm_qkv_kernel(
    const short* __restrict__ hbf, const short* __restrict__ Wt,
    short* __restrict__ Qrm, short* __restrict__ Krm, short* __restrict__ VT) {
    const int z = blockIdx.z;
    const short* Bt = Wt + (size_t)z * cM * cIn;
    const int m0 = blockIdx.y * 128, c0 = blockIdx.x * 128;
    __shared__ short smem[8192];
    const int tid = threadIdx.x, w = tid >> 6, l = tid & 63;
    const int m16 = l & 15, g = l >> 4;
    const int mq = (w & 1) * 64, nq = (w >> 1) * 64;
    f32x4 acc[4][4] = {};

    if (z <= 1) {
        gemm_core<false>(hbf, Bt, smem, m0, c0, tid, acc);
        short* dst = (z == 0) ? Qrm : Krm;
        #pragma unroll
        for (int i = 0; i < 4; i++)
            #pragma unroll
            for (int j = 0; j < 4; j++)
                #pragma unroll
                for (int r = 0; r < 4; r++)
                    dst[(size_t)(m0 + mq + i * 16 + g * 4 + r) * cM +
                        c0 + nq + j * 16 + m16] = f2bf(acc[i][j][r]);
    } else {
        gemm_core<true>(hbf, Bt, smem, m0, c0, tid, acc);
        #pragma unroll
        for (int i = 0; i < 4; i++) {
            const int srow_g = m0 + mq + i * 16 + m16;   // b*S + s
            const int bb = srow_g >> 11, ss = srow_g & 2047;
            #pragma unroll
            for (int j = 0; j < 4; j++)
                #pragma unroll
                for (int r = 0; r < 4; r++) {
                    const int wcol = c0 + nq + j * 16 + g * 4 + r;  // h*64+d
                    VT[(((size_t)bb * cH + (wcol >> 6)) * cD + (wcol & 63)) * cS
                       + ss] = f2bf(acc[i][j][r]);
                }
        }
    }
}

// ---------------------------------------------------------------------------
// Kernel 4: flash attention.
// - register-prefetch pipeline: tile t+1 global loads issued right after
//   staging barrier, consumed at t+1's LDS write (latency hidden by compute)
// - bias+mask folded into MFMA acc-init; exp2 (log2e prefolded into Q & bias)
// - lsum via ones-MFMA (matrix pipe), no end shuffle
// ---------------------------------------------------------------------------
__global__ __launch_bounds__(256) void attn_kernel(
    const short* __restrict__ Qrm, const short* __restrict__ Krm,
    const short* __restrict__ VT, const float* __restrict__ maskadd,
    const float* __restrict__ bias_t, short* __restrict__ ctx) {
    const int b = blockIdx.z, h = blockIdx.y;
    const int q0 = blockIdx.x * 64;
    const short* VTp = VT + ((size_t)b * cH + h) * cS * cD;   // [d][s]
    const float* bh = bias_t + h * 4096 + 2048;
    const float* mp = maskadd + b * cS;

    const int tid = threadIdx.x;
    const int wave = tid >> 6, lane = tid & 63;
    const int m16 = lane & 15, g = lane >> 4;

    __shared__ short Kt[64][72];       // [key][d]
    __shared__ short Vt[64][72];       // [d][kappa]

    const int q = q0 + wave * 16 + m16;          // this thread's q row
    const short* qb = Qrm + (size_t)(b * cS + q) * cM + h * cD;
    bf16x8 qf0 = *(const bf16x8*)(qb + g * 8);
    bf16x8 qf1 = *(const bf16x8*)(qb + 32 + g * 8);

    f32x4 o[4] = {};
    f32x4 lacc = {};
    BfPack ones;
    #pragma unroll
    for (int i = 0; i < 8; i++) ones.s[i] = (short)0x3F80;   // bf16 1.0

    const int srow = tid >> 3;               // 0..31
    const int scol = (tid & 7) << 3;         // 0,8,..,56
    const int kb = ((scol >> 4) & 1) * 32 + ((scol >> 3) & 1) * 16 +
                   ((scol >> 5) & 1) * 4;
    const short* kbase = Krm + (size_t)b * cS * cM + h * cD;

    // prologue: tile 0 into registers
    bf16x8 kr0 = *(const bf16x8*)(kbase + (size_t)srow * cM + scol);
    bf16x8 kr1 = *(const bf16x8*)(kbase + (size_t)(srow + 32) * cM + scol);
    bf16x8 vr0 = *(const bf16x8*)(VTp + (size_t)srow * cS + scol);
    bf16x8 vr1 = *(const bf16x8*)(VTp + (size_t)(srow + 32) * cS + scol);

    for (int kt = 0; kt < cS; kt += 64) {
        __syncthreads();                 // previous tile's compute done
        *(bf16x8*)&Kt[srow][scol] = kr0;
        *(bf16x8*)&Kt[srow + 32][scol] = kr1;
        {
            BfPack v0, v1; v0.v = vr0; v1.v = vr1;
            BfPack4 a, b2, c, d;
            #pragma unroll
            for (int i = 0; i < 4; i++) { a.s[i] = v0.s[i]; b2.s[i] = v0.s[4 + i]; }
            #pragma unroll
            for (int i = 0; i < 4; i++) { c.s[i] = v1.s[i]; d.s[i] = v1.s[4 + i]; }
            *(s16x4*)&Vt[srow][kb]          = a.v;
            *(s16x4*)&Vt[srow][kb + 8]      = b2.v;
            *(s16x4*)&Vt[srow + 32][kb]     = c.v;
            *(s16x4*)&Vt[srow + 32][kb + 8] = d.v;
        }
        __syncthreads();                 // staging visible

        // prefetch next tile (clamped; last-iter loads are dead but uniform)
        const int ktn = (kt + 64 < cS) ? kt + 64 : 0;
        kr0 = *(const bf16x8*)(kbase + (size_t)(ktn + srow) * cM + scol);
        kr1 = *(const bf16x8*)(kbase + (size_t)(ktn + srow + 32) * cM + scol);
        vr0 = *(const bf16x8*)(VTp + (size_t)srow * cS + ktn + scol);
        vr1 = *(const bf16x8*)(VTp + (size_t)(srow + 32) * cS + ktn + scol);

        // ---- S^T with bias+mask pre-loaded into the accumulator
        f32x4 s[4];
        #pragma unroll
        for (int st = 0; st < 4; st++) {
            const int keyb = kt + st * 16 + g * 4;
            f32x4 init;
            #pragma unroll
            for (int c = 0; c < 4; c++)
                init[c] = bh[keyb + c - q] + mp[keyb + c];
            bf16x8 klo = *(const bf16x8*)&Kt[st * 16 + m16][g * 8];
            bf16x8 khi = *(const bf16x8*)&Kt[st * 16 + m16][32 + g * 8];
            s[st] = mfma16(khi, qf1, mfma16(klo, qf0, init));
        }

        // ---- softmax numerator (exp2), pack P fragments in registers
        BfPack pp[2];
        #pragma unroll
        for (int st = 0; st < 4; st++) {
            #pragma unroll
            for (int r = 0; r < 2; r++) {
                float p0 = __builtin_amdgcn_exp2f(s[st][2 * r]);
                float p1 = __builtin_amdgcn_exp2f(s[st][2 * r + 1]);
                __hip_bfloat162 h2 = __float22bfloat162_rn(float2{p0, p1});
                short2 sp = *(short2*)&h2;
                pp[st & 1].s[(st >> 1) * 4 + 2 * r]     = sp.x;
                pp[st & 1].s[(st >> 1) * 4 + 2 * r + 1] = sp.y;
            }
        }

        // ---- denominator on the matrix pipe: lacc += 1 * P
        lacc = mfma16(ones.v, pp[0].v, lacc);
        lacc = mfma16(ones.v, pp[1].v, lacc);

        // ---- O^T = V^T @ P
        #pragma unroll
        for (int nt = 0; nt < 4; nt++) {
            bf16x8 vlo = *(const bf16x8*)&Vt[nt * 16 + m16][g * 8];
            bf16x8 vhi = *(const bf16x8*)&Vt[nt * 16 + m16][32 + g * 8];
            o[nt] = mfma16(vlo, pp[0].v, o[nt]);
            o[nt] = mfma16(vhi, pp[1].v, o[nt]);
        }
    }

    const float inv = 1.0f / lacc[0];    // all 4 regs identical (ones rows)
    short* cb = ctx + ((size_t)b * cS + q) * cM + h * cD;
    #pragma unroll
    for (int nt = 0; nt < 4; nt++) {
        BfPack4 pk;
        #pragma unroll
        for (int r = 0; r < 4; r++) pk.s[r] = f2bf(o[nt][r] * inv);
        *(s16x4*)(cb + nt * 16 + g * 4) = pk.v;
    }
}

// ---------------------------------------------------------------------------
// Kernel 5: out fp32 = ctx(bf16) @ WoT
// ---------------------------------------------------------------------------
__global__ __launch_bounds__(256) void gemm_o_kernel(
    const short* __restrict__ ctx, const short* __restrict__ WoT,
    float* __restrict__ out) {
    const int m0 = blockIdx.y * 128, c0 = blockIdx.x * 128;
    __shared__ short smem[8192];
    const int tid = threadIdx.x, w = tid >> 6, l = tid & 63;
    const int m16 = l & 15, g = l >> 4;
    const int mq = (w & 1) * 64, nq = (w >> 1) * 64;
    f32x4 acc[4][4] = {};
    gemm_core<false>(ctx, WoT, smem, m0, c0, tid, acc);
    #pragma unroll
    for (int i = 0; i < 4; i++)
        #pragma unroll
        for (int j = 0; j < 4; j++)
            #pragma unroll
            for (int r = 0; r < 4; r++)
                out[(size_t)(m0 + mq + i * 16 + g * 4 + r) * cM +
                    c0 + nq + j * 16 + m16] = acc[i][j][r];
}

extern "C" void kernel_launch(void* const* d_in, const int* in_sizes, int n_in,
                              void* d_out, int out_size, void* d_ws, size_t ws_size,
                              hipStream_t stream) {
    const float* hidden   = (const float*)d_in[0];
    const int*   mask     = (const int*)d_in[1];
    const float* Wq       = (const float*)d_in[2];
    const float* Wk       = (const float*)d_in[3];
    const float* Wv       = (const float*)d_in[4];
    const float* Wo       = (const float*)d_in[5];
    const float* rel_bias = (const float*)d_in[6];
    float* out = (float*)d_out;

    // ws (shorts): hbf/ctx 4M | Wt 4x1M | Q 4M | K 4M | VT 4M | bias 256KB | mask 16KB
    short* hbf_ctx = (short*)d_ws;
    short* Wt  = hbf_ctx + (size_t)4 * 1024 * 1024;
    short* Qrm = Wt  + (size_t)4 * 1024 * 1024;
    short* Krm = Qrm + (size_t)4 * 1024 * 1024;
    short* VT  = Krm + (size_t)4 * 1024 * 1024;
    float* bias_t  = (float*)(VT + (size_t)4 * 1024 * 1024);
    float* maskf   = bias_t + 16 * 4096;

    bias_table_kernel<<<16, 256, 0, stream>>>(rel_bias, mask, bias_t, maskf);
    conv_hidden_kernel<<<2048, 256, 0, stream>>>(hidden, hbf_ctx);
    conv_wt_kernel<<<dim3(16, 16, 4), 256, 0, stream>>>(Wq, Wk, Wv, Wo, Wt);
    gemm_qkv_kernel<<<dim3(8, 32, 3), 256, 0, stream>>>(hbf_ctx, Wt, Qrm, Krm, VT);
    attn_kernel<<<dim3(32, cH, cB), 256, 0, stream>>>(Qrm, Krm, VT, maskf, bias_t,
                                                      hbf_ctx);
    gemm_o_kernel<<<dim3(8, 32), 256, 0, stream>>>(hbf_ctx, Wt + (size_t)3 * 1024 * 1024,
                                                   out);
}